// Round 11
// baseline (273.575 us; speedup 1.0000x reference)
//
#include <hip/hip_runtime.h>
#include <hip/hip_bf16.h>

// LuongAttention: B=16, Tq=512, Tk=2048, D=1024 (fp32 in/out)
// Fast path (ws >= 160 MiB), all-fp16 planes:
//   P0: split_enc_T: enc -> enc_h (fp16) + encT (fp16, transposed); dec h/l; W h
//   K1: dproj_h/l = split(dec @ W_h^T)   gemm_wide<2,1,4>  (128x256, 2-ph dbuf)
//   K2: score = (dproj_h+l) @ enc_h^T    gemm_wide<2,0,4>  (128x256, grid 512,
//       2 blocks/CU co-residency: barrier/staging stalls overlap cross-block)
//   K3: softmax in place + fp16 copy (align_h)
//   K4: ctx = align_h @ encT^T           gemm_wide<1,0,4>  (128x256, 2-ph dbuf)
// fp16-x2 decomposition: A split into fp16 hi+lo (~22 bits), B single fp16.
// GEMM schedule = round-5 proven 2-phase dbuf (phase-split/32x32/3-buf all
// regressed, r6-r8). wa_bias cancels in softmax -> skipped.
// Fallback (<160 MiB): round-1 bf16 kernels (need 32 MiB ws).

typedef float f32x4 __attribute__((ext_vector_type(4)));
typedef _Float16 f16x8 __attribute__((ext_vector_type(8)));
typedef __bf16 bf16x8 __attribute__((ext_vector_type(8)));
typedef unsigned short u16x4 __attribute__((ext_vector_type(4)));
typedef unsigned short u16x8 __attribute__((ext_vector_type(8)));

__device__ inline unsigned short h_bits(_Float16 h) {
    union { _Float16 h; unsigned short u; } v; v.h = h; return v.u;
}
// returns hi fp16 bits in [15:0], lo fp16 bits in [31:16]
__device__ inline unsigned int split_f16(float x) {
    _Float16 h = (_Float16)x;
    _Float16 l = (_Float16)(x - (float)h);
    return (unsigned int)h_bits(h) | ((unsigned int)h_bits(l) << 16);
}

__device__ inline void gload16(const void* g, const void* l) {
    __builtin_amdgcn_global_load_lds(
        (const __attribute__((address_space(1))) unsigned int*)g,
        (__attribute__((address_space(3))) unsigned int*)l, 16, 0, 0);
}

// ---------------- P0: fp32 -> fp16 hi(/lo) split (elementwise) --------------
__global__ __launch_bounds__(256)
void splitf16(const float* __restrict__ x, unsigned short* __restrict__ ho,
              unsigned short* __restrict__ lo, int n8)
{
    int i = blockIdx.x * 256 + threadIdx.x;
    if (i >= n8) return;
    const f32x4* xp = reinterpret_cast<const f32x4*>(x + (size_t)i * 8);
    f32x4 v0 = xp[0], v1 = xp[1];
    u16x8 h, l;
#pragma unroll
    for (int j = 0; j < 4; ++j) {
        unsigned int p0 = split_f16(v0[j]);
        unsigned int p1 = split_f16(v1[j]);
        h[j] = (unsigned short)p0;      l[j] = (unsigned short)(p0 >> 16);
        h[4 + j] = (unsigned short)p1;  l[4 + j] = (unsigned short)(p1 >> 16);
    }
    *reinterpret_cast<u16x8*>(ho + (size_t)i * 8) = h;
    if (lo) *reinterpret_cast<u16x8*>(lo + (size_t)i * 8) = l;
}

// ---- P0 fused: enc fp32 -> enc_h (fp16 row-major) + encT (fp16 transposed) -
// enc [16][2048][1024]; encT [16][1024][2048]. 64x64 tiles.
__global__ __launch_bounds__(256)
void split_enc_T(const float* __restrict__ enc, unsigned short* __restrict__ eh,
                 unsigned short* __restrict__ eT)
{
    __shared__ unsigned short t[64][68];   // [d][k], 68 stride breaks bank alias
    const int b = blockIdx.z;
    const int kb = blockIdx.x * 64;   // Tk
    const int db = blockIdx.y * 64;   // D
    const int r = threadIdx.x >> 4;          // 0..15
    const int c0 = (threadIdx.x & 15) * 4;   // 0..60
    const float* ip = enc + ((size_t)b * 2048 + kb) * 1024 + db;
#pragma unroll
    for (int it = 0; it < 4; ++it) {
        int row = it * 16 + r;
        f32x4 v = *reinterpret_cast<const f32x4*>(ip + (size_t)row * 1024 + c0);
        u16x4 h;
#pragma unroll
        for (int j = 0; j < 4; ++j) h[j] = h_bits((_Float16)v[j]);
        *reinterpret_cast<u16x4*>(eh + ((size_t)b * 2048 + kb + row) * 1024 + db + c0) = h;
#pragma unroll
        for (int j = 0; j < 4; ++j) t[c0 + j][row] = h[j];
    }
    __syncthreads();
    const int d = threadIdx.x >> 2;   // 0..63 (D within tile)
    const int ch = threadIdx.x & 3;   // k-chunk of 16
    unsigned short* op = eT + ((size_t)b * 1024 + db + d) * 2048 + kb + ch * 16;
    u16x8 w0, w1;
#pragma unroll
    for (int j = 0; j < 8; ++j) { w0[j] = t[d][ch * 16 + j]; w1[j] = t[d][ch * 16 + 8 + j]; }
    *reinterpret_cast<u16x8*>(op) = w0;
    *reinterpret_cast<u16x8*>(op + 8) = w1;
}

// ========== wide BT GEMM, fp16, 16x16x32 MFMA, 2-phase dbuf (r5 schedule) ===
// C = (Ah[+Al]) @ Bh^T. A planes [M,K], B plane [N,K] fp16, K%32==0.
// BM=32*AM, BN=256, BK=32, 8 waves (2x4), wave-tile (16*AM)x64, acc[AM][4].
// Row-plane list: rp in [0,BM) = Ah rows, [BM,BM*APL) = Al rows,
// [RA, RA+256) = Bh rows. LDS rows 64B, phys chunk = (kc+(rp>>1))&3
// (conflict-free, measured r4/r5). Linear LDS dest (gload_lds) + pre-swizzled
// global src. 2-phase: stage(next buf) issued BEFORE compute(cur), one
// __syncthreads per K-tile. Grid: 1D nwg (nwg%8==0), XCD-swizzled, m-fastest
// (adjacent blocks share the B-panel -> L2 hits for the 2-blocks/CU case).
// OUTMODE 0: fp32 C. OUTMODE 1: fp16 hi/lo split -> Ch, Cl.
// C/D layout [HW-verified]: col = lane&15, row = (lane>>4)*4 + j.
template<int APL, int OUTMODE, int AM>
__global__ __launch_bounds__(512, 2)
void gemm_wide(const unsigned short* __restrict__ Ah, const unsigned short* __restrict__ Al,
               long long sA,
               const unsigned short* __restrict__ Bh, long long sB,
               float* __restrict__ C, unsigned short* __restrict__ Ch,
               unsigned short* __restrict__ Cl, long long sC,
               int M, int N, int K)
{
    constexpr int BM  = 32 * AM;
    constexpr int RA  = BM * APL;                 // A row-planes
    constexpr int TOT = RA + 256;                 // + B row-planes
    constexpr int NI  = TOT / 128;                // gload16 per thread per tile
    constexpr int BUF = TOT * 32;                 // u16 elems per buffer
    __shared__ unsigned short smem[2 * BUF];

    const int tid = threadIdx.x, lane = tid & 63, wave = tid >> 6;

    // XCD swizzle + batch decode (m-fastest)
    const int nwg = gridDim.x;
    int orig = (blockIdx.x & 7) * (nwg >> 3) + (blockIdx.x >> 3);
    const int mb = M / BM, nb = N >> 8, bpb = mb * nb;
    const int z = orig / bpb, rem = orig - z * bpb;
    const int bm = (rem % mb) * BM, bn = (rem / mb) << 8;

    Ah += (size_t)z * sA; Bh += (size_t)z * sB;
    if (APL == 2) Al += (size_t)z * sA;

    // staging geometry: slot c = i*512+tid -> rp = c>>2, phys slot s = c&3
    // holds global chunk g = (s - (rp>>1)) & 3.
    const unsigned short* src[NI];
    int dst[NI];
#pragma unroll
    for (int i = 0; i < NI; ++i) {
        int c = i * 512 + tid, rp = c >> 2, s = c & 3;
        int g = (s + 4 - ((rp >> 1) & 3)) & 3;
        const unsigned short* bp;
        if (rp < BM)                    bp = Ah + (size_t)(bm + rp) * K;
        else if (APL == 2 && rp < RA)   bp = Al + (size_t)(bm + rp - BM) * K;
        else                            bp = Bh + (size_t)(bn + rp - RA) * K;
        src[i] = bp + g * 8;
        dst[i] = rp * 32 + s * 8;
    }

    const int kcL = lane >> 4, fr = lane & 15;
    const int wrow = (wave >> 2) * (16 * AM);
    const int wcol = (wave & 3) * 64;

    f32x4 acc[AM][4] = {};
    const int nt = K >> 5;
    int cur = 0;

    {   // prologue: stage K-tile 0 into buf 0
#pragma unroll
        for (int i = 0; i < NI; ++i) gload16(src[i], smem + dst[i]);
    }
    __syncthreads();

    for (int t = 0; t < nt; ++t) {
        if (t + 1 < nt) {   // issue next-tile stage BEFORE compute (2-phase)
            const int kt = (t + 1) << 5;
            unsigned short* bx = smem + (cur ^ 1) * BUF;
#pragma unroll
            for (int i = 0; i < NI; ++i) gload16(src[i] + kt, bx + dst[i]);
        }
        const unsigned short* base = smem + cur * BUF;
        f16x8 bhf[4];
#pragma unroll
        for (int n = 0; n < 4; ++n) {
            int rp = RA + wcol + n * 16 + fr;
            bhf[n] = *reinterpret_cast<const f16x8*>(base + rp * 32 + (((kcL + (rp >> 1)) & 3) << 3));
        }
#pragma unroll
        for (int m = 0; m < AM; ++m) {
            int ra = wrow + m * 16 + fr;
            f16x8 ah = *reinterpret_cast<const f16x8*>(base + ra * 32 + (((kcL + (ra >> 1)) & 3) << 3));
            f16x8 al;
            if (APL == 2) {
                int rp = BM + ra;
                al = *reinterpret_cast<const f16x8*>(base + rp * 32 + (((kcL + (rp >> 1)) & 3) << 3));
            }
#pragma unroll
            for (int n = 0; n < 4; ++n) {
                acc[m][n] = __builtin_amdgcn_mfma_f32_16x16x32_f16(ah, bhf[n], acc[m][n], 0, 0, 0);
                if (APL == 2)
                    acc[m][n] = __builtin_amdgcn_mfma_f32_16x16x32_f16(al, bhf[n], acc[m][n], 0, 0, 0);
            }
        }
        __syncthreads();   // drains vmcnt: next buf staged; reads of cur done
        cur ^= 1;
    }

    // C/D layout: col = lane&15, row = (lane>>4)*4 + j  [HW-verified]
    if constexpr (OUTMODE == 0) {
        float* Cz = C + (size_t)z * sC;
#pragma unroll
        for (int m = 0; m < AM; ++m)
#pragma unroll
            for (int j = 0; j < 4; ++j) {
                int grow = bm + wrow + m * 16 + (lane >> 4) * 4 + j;
                float* cr = Cz + (size_t)grow * N + bn + wcol + fr;
#pragma unroll
                for (int n = 0; n < 4; ++n) cr[n * 16] = acc[m][n][j];
            }
    } else {
        unsigned short* Chz = Ch + (size_t)z * sC;
        unsigned short* Clz = Cl + (size_t)z * sC;
#pragma unroll
        for (int m = 0; m < AM; ++m)
#pragma unroll
            for (int j = 0; j < 4; ++j) {
                int grow = bm + wrow + m * 16 + (lane >> 4) * 4 + j;
                size_t rb = (size_t)grow * N + bn + wcol + fr;
#pragma unroll
                for (int n = 0; n < 4; ++n) {
                    unsigned int p = split_f16(acc[m][n][j]);
                    Chz[rb + n * 16] = (unsigned short)p;
                    Clz[rb + n * 16] = (unsigned short)(p >> 16);
                }
            }
    }
}

// ---------------- softmax rows (2048 cols) + optional fp16 copy -------------
__global__ __launch_bounds__(256)
void softmax_rows(float* __restrict__ P, unsigned short* __restrict__ alh)
{
    __shared__ float redm[4], reds[4];
    float* p = P + (size_t)blockIdx.x * 2048;
    const int tid = threadIdx.x, lane = tid & 63, wave = tid >> 6;

    f32x4 v0 = *reinterpret_cast<const f32x4*>(p + tid * 4);
    f32x4 v1 = *reinterpret_cast<const f32x4*>(p + 1024 + tid * 4);

    float mx = fmaxf(fmaxf(fmaxf(v0[0], v0[1]), fmaxf(v0[2], v0[3])),
                     fmaxf(fmaxf(v1[0], v1[1]), fmaxf(v1[2], v1[3])));
#pragma unroll
    for (int o = 32; o; o >>= 1) mx = fmaxf(mx, __shfl_xor(mx, o));
    if (lane == 0) redm[wave] = mx;
    __syncthreads();
    mx = fmaxf(fmaxf(redm[0], redm[1]), fmaxf(redm[2], redm[3]));

    float s = 0.f;
#pragma unroll
    for (int j = 0; j < 4; ++j) { v0[j] = __expf(v0[j] - mx); s += v0[j]; }
#pragma unroll
    for (int j = 0; j < 4; ++j) { v1[j] = __expf(v1[j] - mx); s += v1[j]; }
#pragma unroll
    for (int o = 32; o; o >>= 1) s += __shfl_xor(s, o);
    if (lane == 0) reds[wave] = s;
    __syncthreads();
    s = reds[0] + reds[1] + reds[2] + reds[3];

    const float inv = 1.0f / s;
#pragma unroll
    for (int j = 0; j < 4; ++j) { v0[j] *= inv; v1[j] *= inv; }
    *reinterpret_cast<f32x4*>(p + tid * 4) = v0;
    *reinterpret_cast<f32x4*>(p + 1024 + tid * 4) = v1;

    if (alh) {
        unsigned short* ab = alh + (size_t)blockIdx.x * 2048;
        u16x4 h0, h1;
#pragma unroll
        for (int j = 0; j < 4; ++j) {
            h0[j] = h_bits((_Float16)v0[j]);
            h1[j] = h_bits((_Float16)v1[j]);
        }
        *reinterpret_cast<u16x4*>(ab + tid * 4) = h0;
        *reinterpret_cast<u16x4*>(ab + 1024 + tid * 4) = h1;
    }
}

// ======================= round-1 fallback kernels (bf16) ====================
__device__ inline unsigned short f2bf(float f) {
    union { float f; unsigned int u; } v; v.f = f;
    unsigned int r = v.u + 0x7fffu + ((v.u >> 16) & 1u);
    return (unsigned short)(r >> 16);
}
__device__ inline float bf2f(unsigned short h) {
    union { unsigned int u; float f; } v; v.u = ((unsigned int)h) << 16; return v.f;
}
__device__ inline int tile_byte(int row, int kElem) {
    int chunk = kElem >> 3;
    return row * 128 + ((chunk ^ (row & 7)) << 4) + ((kElem & 7) << 1);
}

__global__ __launch_bounds__(256, 2)
void gemm_bt_x3(const float* __restrict__ A, long long sA,
                const float* __restrict__ Bt, long long sB,
                float* __restrict__ C, long long sC,
                int M, int N, int K)
{
    __shared__ unsigned short Ah[128 * 64], Al[128 * 64];
    __shared__ unsigned short Bh[128 * 64], Bl[128 * 64];

    const int tid = threadIdx.x, lane = tid & 63, wave = tid >> 6;
    const int wr = (wave >> 1) * 64, wc = (wave & 1) * 64;
    const int bm = blockIdx.y * 128, bn = blockIdx.x * 128;
    A += (size_t)blockIdx.z * sA;
    Bt += (size_t)blockIdx.z * sB;
    C += (size_t)blockIdx.z * sC;

    f32x4 acc[4][4] = {};

    for (int kt = 0; kt < K; kt += 64) {
#pragma unroll
        for (int i = 0; i < 8; ++i) {
            int idx = tid + i * 256;
            int row = idx >> 4, f4 = idx & 15;
            f32x4 va = *reinterpret_cast<const f32x4*>(A + (size_t)(bm + row) * K + kt + f4 * 4);
            f32x4 vb = *reinterpret_cast<const f32x4*>(Bt + (size_t)(bn + row) * K + kt + f4 * 4);
            u16x4 ah, al, bh, bl;
#pragma unroll
            for (int j = 0; j < 4; ++j) {
                unsigned short h = f2bf(va[j]);
                ah[j] = h; al[j] = f2bf(va[j] - bf2f(h));
                h = f2bf(vb[j]);
                bh[j] = h; bl[j] = f2bf(vb[j] - bf2f(h));
            }
            int off = tile_byte(row, f4 * 4);
            *reinterpret_cast<u16x4*>((char*)Ah + off) = ah;
            *reinterpret_cast<u16x4*>((char*)Al + off) = al;
            *reinterpret_cast<u16x4*>((char*)Bh + off) = bh;
            *reinterpret_cast<u16x4*>((char*)Bl + off) = bl;
        }
        __syncthreads();
#pragma unroll
        for (int kk = 0; kk < 2; ++kk) {
            bf16x8 a_h[4], a_l[4], b_h[4], b_l[4];
            const int kbase = kk * 32 + (lane >> 4) * 8;
#pragma unroll
            for (int m = 0; m < 4; ++m) {
                int off = tile_byte(wr + m * 16 + (lane & 15), kbase);
                a_h[m] = *reinterpret_cast<const bf16x8*>((char*)Ah + off);
                a_l[m] = *reinterpret_cast<const bf16x8*>((char*)Al + off);
            }
#pragma unroll
            for (int n = 0; n < 4; ++n) {
                int off = tile_byte(wc + n * 16 + (lane & 15), kbase);
                b_h[n] = *reinterpret_cast<const bf16x8*>((char*)Bh + off);
                b_l[n] = *reinterpret_cast<const bf16x8*>((char*)Bl + off);
            }
#pragma unroll
            for (int m = 0; m < 4; ++m)
#pragma unroll
                for (int n = 0; n < 4; ++n) {
                    acc[m][n] = __builtin_amdgcn_mfma_f32_16x16x32_bf16(a_h[m], b_h[n], acc[m][n], 0, 0, 0);
                    acc[m][n] = __builtin_amdgcn_mfma_f32_16x16x32_bf16(a_h[m], b_l[n], acc[m][n], 0, 0, 0);
                    acc[m][n] = __builtin_amdgcn_mfma_f32_16x16x32_bf16(a_l[m], b_h[n], acc[m][n], 0, 0, 0);
                }
        }
        __syncthreads();
    }
#pragma unroll
    for (int m = 0; m < 4; ++m)
#pragma unroll
        for (int j = 0; j < 4; ++j) {
            int grow = bm + wr + m * 16 + (lane >> 4) * 4 + j;
            float* cr = C + (size_t)grow * N + bn + wc + (lane & 15);
#pragma unroll
            for (int n = 0; n < 4; ++n) cr[n * 16] = acc[m][n][j];
        }
}

__global__ __launch_bounds__(256, 2)
void gemm_nn_bf16(const float* __restrict__ A, long long sA,
                  const float* __restrict__ Bn, long long sB,
                  float* __restrict__ C, long long sC,
                  int M, int N, int K)
{
    __shared__ unsigned short As[128 * 64];
    __shared__ unsigned short Bs[64 * 130];

    const int tid = threadIdx.x, lane = tid & 63, wave = tid >> 6;
    const int wr = (wave >> 1) * 64, wc = (wave & 1) * 64;
    const int bm = blockIdx.y * 128, bn = blockIdx.x * 128;
    A += (size_t)blockIdx.z * sA;
    Bn += (size_t)blockIdx.z * sB;
    C += (size_t)blockIdx.z * sC;

    f32x4 acc[4][4] = {};

    for (int kt = 0; kt < K; kt += 64) {
#pragma unroll
        for (int i = 0; i < 8; ++i) {
            int idx = tid + i * 256;
            int row = idx >> 4, f4 = idx & 15;
            f32x4 va = *reinterpret_cast<const f32x4*>(A + (size_t)(bm + row) * K + kt + f4 * 4);
            u16x4 h;
#pragma unroll
            for (int j = 0; j < 4; ++j) h[j] = f2bf(va[j]);
            *reinterpret_cast<u16x4*>((char*)As + tile_byte(row, f4 * 4)) = h;
        }
#pragma unroll
        for (int i = 0; i < 8; ++i) {
            int idx = tid + i * 256;
            int krow = idx >> 5, f4 = idx & 31;
            f32x4 vb = *reinterpret_cast<const f32x4*>(Bn + (size_t)(kt + krow) * N + bn + f4 * 4);
            unsigned int p0 = (unsigned int)f2bf(vb[0]) | ((unsigned int)f2bf(vb[1]) << 16);
            unsigned int p1 = (unsigned int)f2bf(vb[2]) | ((unsigned int)f2bf(vb[3]) << 16);
            unsigned int* bp = reinterpret_cast<unsigned int*>(&Bs[krow * 130 + f4 * 4]);
            bp[0] = p0; bp[1] = p1;
        }
        __syncthreads();
#pragma unroll
        for (int kk = 0; kk < 2; ++kk) {
            bf16x8 a[4], b[4];
            const int kbase = kk * 32 + (lane >> 4) * 8;
#pragma unroll
            for (int m = 0; m < 4; ++m)
                a[m] = *reinterpret_cast<const bf16x8*>((char*)As + tile_byte(wr + m * 16 + (lane & 15), kbase));
#pragma unroll
            for (int n = 0; n < 4; ++n) {
                int col = wc + n * 16 + (lane & 15);
                union { unsigned short u[8]; bf16x8 v; } t;
#pragma unroll
                for (int j = 0; j < 8; ++j) t.u[j] = Bs[(kbase + j) * 130 + col];
                b[n] = t.v;
            }
#pragma unroll
            for (int m = 0; m < 4; ++m)
#pragma unroll
                for (int n = 0; n < 4; ++n)
                    acc[m][n] = __builtin_amdgcn_mfma_f32_16x16x32_bf16(a[m], b[n], acc[m][n], 0, 0, 0);
        }
        __syncthreads();
    }
#pragma unroll
    for (int m = 0; m < 4; ++m)
#pragma unroll
        for (int j = 0; j < 4; ++j) {
            int grow = bm + wr + m * 16 + (lane >> 4) * 4 + j;
            float* cr = C + (size_t)grow * N + bn + wc + (lane & 15);
#pragma unroll
            for (int n = 0; n < 4; ++n) cr[n * 16] = acc[m][n][j];
        }
}

// ============================================================================
extern "C" void kernel_launch(void* const* d_in, const int* in_sizes, int n_in,
                              void* d_out, int out_size, void* d_ws, size_t ws_size,
                              hipStream_t stream)
{
    (void)in_sizes; (void)n_in; (void)out_size;
    const float* dec = (const float*)d_in[0];   // [16,512,1024]
    const float* enc = (const float*)d_in[1];   // [16,2048,1024]
    const float* W   = (const float*)d_in[2];   // [1024,1024]

    float* ctx   = (float*)d_out;                            // [16,512,1024]
    float* align = (float*)d_out + (size_t)16 * 512 * 1024;  // [16,512,2048]

    const size_t NEED_FAST = 160ULL * 1048576ULL;  // enc_h + encT + align_h

    if (ws_size >= NEED_FAST) {
        unsigned short* enc_h   = (unsigned short*)d_ws;             // 64 MiB
        unsigned short* encT    = enc_h + 33554432ULL;               // 64 MiB
        unsigned short* align_h = encT + 33554432ULL;                // 32 MiB
        unsigned short* dproj_h = (unsigned short*)d_out;            // ctx region (dead until K4)
        unsigned short* dproj_l = dproj_h + 8388608ULL;
        unsigned short* dec_h   = (unsigned short*)align;            // align region (dead until K2)
        unsigned short* dec_l   = dec_h + 8388608ULL;
        unsigned short* W_h     = dec_l + 8388608ULL;

        // P0: enc -> enc_h + encT (fused transpose); dec h/l; W h only
        split_enc_T<<<dim3(32, 16, 16), 256, 0, stream>>>(enc, enc_h, encT);
        splitf16<<<4096, 256, 0, stream>>>(dec, dec_h, dec_l, 1048576);
        splitf16<<<512, 256, 0, stream>>>(W, W_h, nullptr, 131072);

        // K1: dproj = dec @ W_h^T  (M=8192, N=1024, K=1024) -> fp16 h/l planes
        gemm_wide<2, 1, 4><<<256, 512, 0, stream>>>(
            dec_h, dec_l, 0, W_h, 0,
            nullptr, dproj_h, dproj_l, 0, 8192, 1024, 1024);

        // K2: score = dproj @ enc_h^T per batch (M=512, N=2048, K=1024) -> align
        // BM=128 -> grid 512 = 2 blocks/CU (64 KB LDS): cross-block overlap of
        // barrier/staging stalls (was 96 KB, 1 block/CU at BM=256)
        gemm_wide<2, 0, 4><<<512, 512, 0, stream>>>(
            dproj_h, dproj_l, 512LL * 1024, enc_h, 2048LL * 1024,
            align, nullptr, nullptr, 512LL * 2048, 512, 2048, 1024);

        // K3: softmax + fp16 copy
        softmax_rows<<<8192, 256, 0, stream>>>(align, align_h);

        // K4: ctx = align_h @ encT^T per batch (M=512, N=1024, K=2048)
        gemm_wide<1, 0, 4><<<256, 512, 0, stream>>>(
            align_h, nullptr, 512LL * 2048, encT, 1024LL * 2048,
            ctx, nullptr, nullptr, 512LL * 1024, 512, 1024, 2048);
    } else {
        // round-1 fallback (needs 32 MiB ws)
        float* dproj = (float*)d_ws;
        gemm_bt_x3<<<dim3(8, 64, 1), 256, 0, stream>>>(
            dec, 0, W, 0, dproj, 0, 8192, 1024, 1024);
        gemm_bt_x3<<<dim3(16, 4, 16), 256, 0, stream>>>(
            dproj, 512LL * 1024, enc, 2048LL * 1024, align, 512LL * 2048, 512, 2048, 1024);
        softmax_rows<<<8192, 256, 0, stream>>>(align, nullptr);
        gemm_nn_bf16<<<dim3(8, 4, 16), 256, 0, stream>>>(
            align, 512LL * 2048, enc, 2048LL * 1024, ctx, 512LL * 1024, 512, 1024, 2048);
    }
}

// Round 12
// 266.749 us; speedup vs baseline: 1.0256x; 1.0256x over previous
//
#include <hip/hip_runtime.h>
#include <hip/hip_bf16.h>

// LuongAttention: B=16, Tq=512, Tk=2048, D=1024 (fp32 in/out)
// Fast path (ws >= 160 MiB), all-fp16 planes:  [round-10 best config: 266 us]
//   P0: split_enc_T: enc -> enc_h (fp16) + encT (fp16, transposed); dec h/l; W h
//   K1: dproj_h/l = split(dec @ W_h^T)   gemm_wide<2,1,4>  (128x256, 2-ph dbuf)
//   K2: score = (dproj_h+l) @ enc_h^T    gemm_wide<2,0,8>  (256x256, 2-ph dbuf)
//   K3: softmax in place + fp16 copy (align_h)
//   K4: ctx = align_h @ encT^T           gemm_wide<1,0,4>  (128x256, 2-ph dbuf)
// fp16-x2 decomposition: A split into fp16 hi+lo (~22 bits), B single fp16.
// Schedule variants all regressed vs this: drain-0 phase-split (r6), 32x32
// frags (r7, 4-way LDS conflict), 3-buf counted-vmcnt (r8, LDS-bound at
// BM=128), small-tile 2-blk/CU (r11, surface/volume loss). wa_bias cancels
// in softmax -> skipped. Fallback (<160 MiB): round-1 bf16 kernels.

typedef float f32x4 __attribute__((ext_vector_type(4)));
typedef _Float16 f16x8 __attribute__((ext_vector_type(8)));
typedef __bf16 bf16x8 __attribute__((ext_vector_type(8)));
typedef unsigned short u16x4 __attribute__((ext_vector_type(4)));
typedef unsigned short u16x8 __attribute__((ext_vector_type(8)));

__device__ inline unsigned short h_bits(_Float16 h) {
    union { _Float16 h; unsigned short u; } v; v.h = h; return v.u;
}
// returns hi fp16 bits in [15:0], lo fp16 bits in [31:16]
__device__ inline unsigned int split_f16(float x) {
    _Float16 h = (_Float16)x;
    _Float16 l = (_Float16)(x - (float)h);
    return (unsigned int)h_bits(h) | ((unsigned int)h_bits(l) << 16);
}

__device__ inline void gload16(const void* g, const void* l) {
    __builtin_amdgcn_global_load_lds(
        (const __attribute__((address_space(1))) unsigned int*)g,
        (__attribute__((address_space(3))) unsigned int*)l, 16, 0, 0);
}

// ---------------- P0: fp32 -> fp16 hi(/lo) split (elementwise) --------------
__global__ __launch_bounds__(256)
void splitf16(const float* __restrict__ x, unsigned short* __restrict__ ho,
              unsigned short* __restrict__ lo, int n8)
{
    int i = blockIdx.x * 256 + threadIdx.x;
    if (i >= n8) return;
    const f32x4* xp = reinterpret_cast<const f32x4*>(x + (size_t)i * 8);
    f32x4 v0 = xp[0], v1 = xp[1];
    u16x8 h, l;
#pragma unroll
    for (int j = 0; j < 4; ++j) {
        unsigned int p0 = split_f16(v0[j]);
        unsigned int p1 = split_f16(v1[j]);
        h[j] = (unsigned short)p0;      l[j] = (unsigned short)(p0 >> 16);
        h[4 + j] = (unsigned short)p1;  l[4 + j] = (unsigned short)(p1 >> 16);
    }
    *reinterpret_cast<u16x8*>(ho + (size_t)i * 8) = h;
    if (lo) *reinterpret_cast<u16x8*>(lo + (size_t)i * 8) = l;
}

// ---- P0 fused: enc fp32 -> enc_h (fp16 row-major) + encT (fp16 transposed) -
// enc [16][2048][1024]; encT [16][1024][2048]. 64x64 tiles.
__global__ __launch_bounds__(256)
void split_enc_T(const float* __restrict__ enc, unsigned short* __restrict__ eh,
                 unsigned short* __restrict__ eT)
{
    __shared__ unsigned short t[64][68];   // [d][k], 68 stride breaks bank alias
    const int b = blockIdx.z;
    const int kb = blockIdx.x * 64;   // Tk
    const int db = blockIdx.y * 64;   // D
    const int r = threadIdx.x >> 4;          // 0..15
    const int c0 = (threadIdx.x & 15) * 4;   // 0..60
    const float* ip = enc + ((size_t)b * 2048 + kb) * 1024 + db;
#pragma unroll
    for (int it = 0; it < 4; ++it) {
        int row = it * 16 + r;
        f32x4 v = *reinterpret_cast<const f32x4*>(ip + (size_t)row * 1024 + c0);
        u16x4 h;
#pragma unroll
        for (int j = 0; j < 4; ++j) h[j] = h_bits((_Float16)v[j]);
        *reinterpret_cast<u16x4*>(eh + ((size_t)b * 2048 + kb + row) * 1024 + db + c0) = h;
#pragma unroll
        for (int j = 0; j < 4; ++j) t[c0 + j][row] = h[j];
    }
    __syncthreads();
    const int d = threadIdx.x >> 2;   // 0..63 (D within tile)
    const int ch = threadIdx.x & 3;   // k-chunk of 16
    unsigned short* op = eT + ((size_t)b * 1024 + db + d) * 2048 + kb + ch * 16;
    u16x8 w0, w1;
#pragma unroll
    for (int j = 0; j < 8; ++j) { w0[j] = t[d][ch * 16 + j]; w1[j] = t[d][ch * 16 + 8 + j]; }
    *reinterpret_cast<u16x8*>(op) = w0;
    *reinterpret_cast<u16x8*>(op + 8) = w1;
}

// ========== wide BT GEMM, fp16, 16x16x32 MFMA, 2-phase dbuf (r5 schedule) ===
// C = (Ah[+Al]) @ Bh^T. A planes [M,K], B plane [N,K] fp16, K%32==0.
// BM=32*AM, BN=256, BK=32, 8 waves (2x4), wave-tile (16*AM)x64, acc[AM][4].
// Row-plane list: rp in [0,BM) = Ah rows, [BM,BM*APL) = Al rows,
// [RA, RA+256) = Bh rows. LDS rows 64B, phys chunk = (kc+(rp>>1))&3
// (conflict-free, measured r4/r5). Linear LDS dest (gload_lds) + pre-swizzled
// global src. 2-phase: stage(next buf) issued BEFORE compute(cur), one
// __syncthreads per K-tile. Grid: 1D nwg (nwg%8==0), XCD-swizzled, m-fastest.
// OUTMODE 0: fp32 C. OUTMODE 1: fp16 hi/lo split -> Ch, Cl.
// C/D layout [HW-verified]: col = lane&15, row = (lane>>4)*4 + j.
template<int APL, int OUTMODE, int AM>
__global__ __launch_bounds__(512, 2)
void gemm_wide(const unsigned short* __restrict__ Ah, const unsigned short* __restrict__ Al,
               long long sA,
               const unsigned short* __restrict__ Bh, long long sB,
               float* __restrict__ C, unsigned short* __restrict__ Ch,
               unsigned short* __restrict__ Cl, long long sC,
               int M, int N, int K)
{
    constexpr int BM  = 32 * AM;
    constexpr int RA  = BM * APL;                 // A row-planes
    constexpr int TOT = RA + 256;                 // + B row-planes
    constexpr int NI  = TOT / 128;                // gload16 per thread per tile
    constexpr int BUF = TOT * 32;                 // u16 elems per buffer
    __shared__ unsigned short smem[2 * BUF];

    const int tid = threadIdx.x, lane = tid & 63, wave = tid >> 6;

    // XCD swizzle + batch decode (m-fastest)
    const int nwg = gridDim.x;
    int orig = (blockIdx.x & 7) * (nwg >> 3) + (blockIdx.x >> 3);
    const int mb = M / BM, nb = N >> 8, bpb = mb * nb;
    const int z = orig / bpb, rem = orig - z * bpb;
    const int bm = (rem % mb) * BM, bn = (rem / mb) << 8;

    Ah += (size_t)z * sA; Bh += (size_t)z * sB;
    if (APL == 2) Al += (size_t)z * sA;

    // staging geometry: slot c = i*512+tid -> rp = c>>2, phys slot s = c&3
    // holds global chunk g = (s - (rp>>1)) & 3.
    const unsigned short* src[NI];
    int dst[NI];
#pragma unroll
    for (int i = 0; i < NI; ++i) {
        int c = i * 512 + tid, rp = c >> 2, s = c & 3;
        int g = (s + 4 - ((rp >> 1) & 3)) & 3;
        const unsigned short* bp;
        if (rp < BM)                    bp = Ah + (size_t)(bm + rp) * K;
        else if (APL == 2 && rp < RA)   bp = Al + (size_t)(bm + rp - BM) * K;
        else                            bp = Bh + (size_t)(bn + rp - RA) * K;
        src[i] = bp + g * 8;
        dst[i] = rp * 32 + s * 8;
    }

    const int kcL = lane >> 4, fr = lane & 15;
    const int wrow = (wave >> 2) * (16 * AM);
    const int wcol = (wave & 3) * 64;

    f32x4 acc[AM][4] = {};
    const int nt = K >> 5;
    int cur = 0;

    {   // prologue: stage K-tile 0 into buf 0
#pragma unroll
        for (int i = 0; i < NI; ++i) gload16(src[i], smem + dst[i]);
    }
    __syncthreads();

    for (int t = 0; t < nt; ++t) {
        if (t + 1 < nt) {   // issue next-tile stage BEFORE compute (2-phase)
            const int kt = (t + 1) << 5;
            unsigned short* bx = smem + (cur ^ 1) * BUF;
#pragma unroll
            for (int i = 0; i < NI; ++i) gload16(src[i] + kt, bx + dst[i]);
        }
        const unsigned short* base = smem + cur * BUF;
        f16x8 bhf[4];
#pragma unroll
        for (int n = 0; n < 4; ++n) {
            int rp = RA + wcol + n * 16 + fr;
            bhf[n] = *reinterpret_cast<const f16x8*>(base + rp * 32 + (((kcL + (rp >> 1)) & 3) << 3));
        }
#pragma unroll
        for (int m = 0; m < AM; ++m) {
            int ra = wrow + m * 16 + fr;
            f16x8 ah = *reinterpret_cast<const f16x8*>(base + ra * 32 + (((kcL + (ra >> 1)) & 3) << 3));
            f16x8 al;
            if (APL == 2) {
                int rp = BM + ra;
                al = *reinterpret_cast<const f16x8*>(base + rp * 32 + (((kcL + (rp >> 1)) & 3) << 3));
            }
#pragma unroll
            for (int n = 0; n < 4; ++n) {
                acc[m][n] = __builtin_amdgcn_mfma_f32_16x16x32_f16(ah, bhf[n], acc[m][n], 0, 0, 0);
                if (APL == 2)
                    acc[m][n] = __builtin_amdgcn_mfma_f32_16x16x32_f16(al, bhf[n], acc[m][n], 0, 0, 0);
            }
        }
        __syncthreads();   // drains vmcnt: next buf staged; reads of cur done
        cur ^= 1;
    }

    // C/D layout: col = lane&15, row = (lane>>4)*4 + j  [HW-verified]
    if constexpr (OUTMODE == 0) {
        float* Cz = C + (size_t)z * sC;
#pragma unroll
        for (int m = 0; m < AM; ++m)
#pragma unroll
            for (int j = 0; j < 4; ++j) {
                int grow = bm + wrow + m * 16 + (lane >> 4) * 4 + j;
                float* cr = Cz + (size_t)grow * N + bn + wcol + fr;
#pragma unroll
                for (int n = 0; n < 4; ++n) cr[n * 16] = acc[m][n][j];
            }
    } else {
        unsigned short* Chz = Ch + (size_t)z * sC;
        unsigned short* Clz = Cl + (size_t)z * sC;
#pragma unroll
        for (int m = 0; m < AM; ++m)
#pragma unroll
            for (int j = 0; j < 4; ++j) {
                int grow = bm + wrow + m * 16 + (lane >> 4) * 4 + j;
                size_t rb = (size_t)grow * N + bn + wcol + fr;
#pragma unroll
                for (int n = 0; n < 4; ++n) {
                    unsigned int p = split_f16(acc[m][n][j]);
                    Chz[rb + n * 16] = (unsigned short)p;
                    Clz[rb + n * 16] = (unsigned short)(p >> 16);
                }
            }
    }
}

// ---------------- softmax rows (2048 cols) + optional fp16 copy -------------
__global__ __launch_bounds__(256)
void softmax_rows(float* __restrict__ P, unsigned short* __restrict__ alh)
{
    __shared__ float redm[4], reds[4];
    float* p = P + (size_t)blockIdx.x * 2048;
    const int tid = threadIdx.x, lane = tid & 63, wave = tid >> 6;

    f32x4 v0 = *reinterpret_cast<const f32x4*>(p + tid * 4);
    f32x4 v1 = *reinterpret_cast<const f32x4*>(p + 1024 + tid * 4);

    float mx = fmaxf(fmaxf(fmaxf(v0[0], v0[1]), fmaxf(v0[2], v0[3])),
                     fmaxf(fmaxf(v1[0], v1[1]), fmaxf(v1[2], v1[3])));
#pragma unroll
    for (int o = 32; o; o >>= 1) mx = fmaxf(mx, __shfl_xor(mx, o));
    if (lane == 0) redm[wave] = mx;
    __syncthreads();
    mx = fmaxf(fmaxf(redm[0], redm[1]), fmaxf(redm[2], redm[3]));

    float s = 0.f;
#pragma unroll
    for (int j = 0; j < 4; ++j) { v0[j] = __expf(v0[j] - mx); s += v0[j]; }
#pragma unroll
    for (int j = 0; j < 4; ++j) { v1[j] = __expf(v1[j] - mx); s += v1[j]; }
#pragma unroll
    for (int o = 32; o; o >>= 1) s += __shfl_xor(s, o);
    if (lane == 0) reds[wave] = s;
    __syncthreads();
    s = reds[0] + reds[1] + reds[2] + reds[3];

    const float inv = 1.0f / s;
#pragma unroll
    for (int j = 0; j < 4; ++j) { v0[j] *= inv; v1[j] *= inv; }
    *reinterpret_cast<f32x4*>(p + tid * 4) = v0;
    *reinterpret_cast<f32x4*>(p + 1024 + tid * 4) = v1;

    if (alh) {
        unsigned short* ab = alh + (size_t)blockIdx.x * 2048;
        u16x4 h0, h1;
#pragma unroll
        for (int j = 0; j < 4; ++j) {
            h0[j] = h_bits((_Float16)v0[j]);
            h1[j] = h_bits((_Float16)v1[j]);
        }
        *reinterpret_cast<u16x4*>(ab + tid * 4) = h0;
        *reinterpret_cast<u16x4*>(ab + 1024 + tid * 4) = h1;
    }
}

// ======================= round-1 fallback kernels (bf16) ====================
__device__ inline unsigned short f2bf(float f) {
    union { float f; unsigned int u; } v; v.f = f;
    unsigned int r = v.u + 0x7fffu + ((v.u >> 16) & 1u);
    return (unsigned short)(r >> 16);
}
__device__ inline float bf2f(unsigned short h) {
    union { unsigned int u; float f; } v; v.u = ((unsigned int)h) << 16; return v.f;
}
__device__ inline int tile_byte(int row, int kElem) {
    int chunk = kElem >> 3;
    return row * 128 + ((chunk ^ (row & 7)) << 4) + ((kElem & 7) << 1);
}

__global__ __launch_bounds__(256, 2)
void gemm_bt_x3(const float* __restrict__ A, long long sA,
                const float* __restrict__ Bt, long long sB,
                float* __restrict__ C, long long sC,
                int M, int N, int K)
{
    __shared__ unsigned short Ah[128 * 64], Al[128 * 64];
    __shared__ unsigned short Bh[128 * 64], Bl[128 * 64];

    const int tid = threadIdx.x, lane = tid & 63, wave = tid >> 6;
    const int wr = (wave >> 1) * 64, wc = (wave & 1) * 64;
    const int bm = blockIdx.y * 128, bn = blockIdx.x * 128;
    A += (size_t)blockIdx.z * sA;
    Bt += (size_t)blockIdx.z * sB;
    C += (size_t)blockIdx.z * sC;

    f32x4 acc[4][4] = {};

    for (int kt = 0; kt < K; kt += 64) {
#pragma unroll
        for (int i = 0; i < 8; ++i) {
            int idx = tid + i * 256;
            int row = idx >> 4, f4 = idx & 15;
            f32x4 va = *reinterpret_cast<const f32x4*>(A + (size_t)(bm + row) * K + kt + f4 * 4);
            f32x4 vb = *reinterpret_cast<const f32x4*>(Bt + (size_t)(bn + row) * K + kt + f4 * 4);
            u16x4 ah, al, bh, bl;
#pragma unroll
            for (int j = 0; j < 4; ++j) {
                unsigned short h = f2bf(va[j]);
                ah[j] = h; al[j] = f2bf(va[j] - bf2f(h));
                h = f2bf(vb[j]);
                bh[j] = h; bl[j] = f2bf(vb[j] - bf2f(h));
            }
            int off = tile_byte(row, f4 * 4);
            *reinterpret_cast<u16x4*>((char*)Ah + off) = ah;
            *reinterpret_cast<u16x4*>((char*)Al + off) = al;
            *reinterpret_cast<u16x4*>((char*)Bh + off) = bh;
            *reinterpret_cast<u16x4*>((char*)Bl + off) = bl;
        }
        __syncthreads();
#pragma unroll
        for (int kk = 0; kk < 2; ++kk) {
            bf16x8 a_h[4], a_l[4], b_h[4], b_l[4];
            const int kbase = kk * 32 + (lane >> 4) * 8;
#pragma unroll
            for (int m = 0; m < 4; ++m) {
                int off = tile_byte(wr + m * 16 + (lane & 15), kbase);
                a_h[m] = *reinterpret_cast<const bf16x8*>((char*)Ah + off);
                a_l[m] = *reinterpret_cast<const bf16x8*>((char*)Al + off);
            }
#pragma unroll
            for (int n = 0; n < 4; ++n) {
                int off = tile_byte(wc + n * 16 + (lane & 15), kbase);
                b_h[n] = *reinterpret_cast<const bf16x8*>((char*)Bh + off);
                b_l[n] = *reinterpret_cast<const bf16x8*>((char*)Bl + off);
            }
#pragma unroll
            for (int m = 0; m < 4; ++m)
#pragma unroll
                for (int n = 0; n < 4; ++n) {
                    acc[m][n] = __builtin_amdgcn_mfma_f32_16x16x32_bf16(a_h[m], b_h[n], acc[m][n], 0, 0, 0);
                    acc[m][n] = __builtin_amdgcn_mfma_f32_16x16x32_bf16(a_h[m], b_l[n], acc[m][n], 0, 0, 0);
                    acc[m][n] = __builtin_amdgcn_mfma_f32_16x16x32_bf16(a_l[m], b_h[n], acc[m][n], 0, 0, 0);
                }
        }
        __syncthreads();
    }
#pragma unroll
    for (int m = 0; m < 4; ++m)
#pragma unroll
        for (int j = 0; j < 4; ++j) {
            int grow = bm + wr + m * 16 + (lane >> 4) * 4 + j;
            float* cr = C + (size_t)grow * N + bn + wc + (lane & 15);
#pragma unroll
            for (int n = 0; n < 4; ++n) cr[n * 16] = acc[m][n][j];
        }
}

__global__ __launch_bounds__(256, 2)
void gemm_nn_bf16(const float* __restrict__ A, long long sA,
                  const float* __restrict__ Bn, long long sB,
                  float* __restrict__ C, long long sC,
                  int M, int N, int K)
{
    __shared__ unsigned short As[128 * 64];
    __shared__ unsigned short Bs[64 * 130];

    const int tid = threadIdx.x, lane = tid & 63, wave = tid >> 6;
    const int wr = (wave >> 1) * 64, wc = (wave & 1) * 64;
    const int bm = blockIdx.y * 128, bn = blockIdx.x * 128;
    A += (size_t)blockIdx.z * sA;
    Bn += (size_t)blockIdx.z * sB;
    C += (size_t)blockIdx.z * sC;

    f32x4 acc[4][4] = {};

    for (int kt = 0; kt < K; kt += 64) {
#pragma unroll
        for (int i = 0; i < 8; ++i) {
            int idx = tid + i * 256;
            int row = idx >> 4, f4 = idx & 15;
            f32x4 va = *reinterpret_cast<const f32x4*>(A + (size_t)(bm + row) * K + kt + f4 * 4);
            u16x4 h;
#pragma unroll
            for (int j = 0; j < 4; ++j) h[j] = f2bf(va[j]);
            *reinterpret_cast<u16x4*>((char*)As + tile_byte(row, f4 * 4)) = h;
        }
#pragma unroll
        for (int i = 0; i < 8; ++i) {
            int idx = tid + i * 256;
            int krow = idx >> 5, f4 = idx & 31;
            f32x4 vb = *reinterpret_cast<const f32x4*>(Bn + (size_t)(kt + krow) * N + bn + f4 * 4);
            unsigned int p0 = (unsigned int)f2bf(vb[0]) | ((unsigned int)f2bf(vb[1]) << 16);
            unsigned int p1 = (unsigned int)f2bf(vb[2]) | ((unsigned int)f2bf(vb[3]) << 16);
            unsigned int* bp = reinterpret_cast<unsigned int*>(&Bs[krow * 130 + f4 * 4]);
            bp[0] = p0; bp[1] = p1;
        }
        __syncthreads();
#pragma unroll
        for (int kk = 0; kk < 2; ++kk) {
            bf16x8 a[4], b[4];
            const int kbase = kk * 32 + (lane >> 4) * 8;
#pragma unroll
            for (int m = 0; m < 4; ++m)
                a[m] = *reinterpret_cast<const bf16x8*>((char*)As + tile_byte(wr + m * 16 + (lane & 15), kbase));
#pragma unroll
            for (int n = 0; n < 4; ++n) {
                int col = wc + n * 16 + (lane & 15);
                union { unsigned short u[8]; bf16x8 v; } t;
#pragma unroll
                for (int j = 0; j < 8; ++j) t.u[j] = Bs[(kbase + j) * 130 + col];
                b[n] = t.v;
            }
#pragma unroll
            for (int m = 0; m < 4; ++m)
#pragma unroll
                for (int n = 0; n < 4; ++n)
                    acc[m][n] = __builtin_amdgcn_mfma_f32_16x16x32_bf16(a[m], b[n], acc[m][n], 0, 0, 0);
        }
        __syncthreads();
    }
#pragma unroll
    for (int m = 0; m < 4; ++m)
#pragma unroll
        for (int j = 0; j < 4; ++j) {
            int grow = bm + wr + m * 16 + (lane >> 4) * 4 + j;
            float* cr = C + (size_t)grow * N + bn + wc + (lane & 15);
#pragma unroll
            for (int n = 0; n < 4; ++n) cr[n * 16] = acc[m][n][j];
        }
}

// ============================================================================
extern "C" void kernel_launch(void* const* d_in, const int* in_sizes, int n_in,
                              void* d_out, int out_size, void* d_ws, size_t ws_size,
                              hipStream_t stream)
{
    (void)in_sizes; (void)n_in; (void)out_size;
    const float* dec = (const float*)d_in[0];   // [16,512,1024]
    const float* enc = (const float*)d_in[1];   // [16,2048,1024]
    const float* W   = (const float*)d_in[2];   // [1024,1024]

    float* ctx   = (float*)d_out;                            // [16,512,1024]
    float* align = (float*)d_out + (size_t)16 * 512 * 1024;  // [16,512,2048]

    const size_t NEED_FAST = 160ULL * 1048576ULL;  // enc_h + encT + align_h

    if (ws_size >= NEED_FAST) {
        unsigned short* enc_h   = (unsigned short*)d_ws;             // 64 MiB
        unsigned short* encT    = enc_h + 33554432ULL;               // 64 MiB
        unsigned short* align_h = encT + 33554432ULL;                // 32 MiB
        unsigned short* dproj_h = (unsigned short*)d_out;            // ctx region (dead until K4)
        unsigned short* dproj_l = dproj_h + 8388608ULL;
        unsigned short* dec_h   = (unsigned short*)align;            // align region (dead until K2)
        unsigned short* dec_l   = dec_h + 8388608ULL;
        unsigned short* W_h     = dec_l + 8388608ULL;

        // P0: enc -> enc_h + encT (fused transpose); dec h/l; W h only
        split_enc_T<<<dim3(32, 16, 16), 256, 0, stream>>>(enc, enc_h, encT);
        splitf16<<<4096, 256, 0, stream>>>(dec, dec_h, dec_l, 1048576);
        splitf16<<<512, 256, 0, stream>>>(W, W_h, nullptr, 131072);

        // K1: dproj = dec @ W_h^T  (M=8192, N=1024, K=1024) -> fp16 h/l planes
        gemm_wide<2, 1, 4><<<256, 512, 0, stream>>>(
            dec_h, dec_l, 0, W_h, 0,
            nullptr, dproj_h, dproj_l, 0, 8192, 1024, 1024);

        // K2: score = dproj @ enc_h^T per batch (M=512, N=2048, K=1024) -> align
        // BM=256, grid 256 (r10 best: 76 us; BM=128/2-blk regressed, r11)
        gemm_wide<2, 0, 8><<<256, 512, 0, stream>>>(
            dproj_h, dproj_l, 512LL * 1024, enc_h, 2048LL * 1024,
            align, nullptr, nullptr, 512LL * 2048, 512, 2048, 1024);

        // K3: softmax + fp16 copy
        softmax_rows<<<8192, 256, 0, stream>>>(align, align_h);

        // K4: ctx = align_h @ encT^T per batch (M=512, N=1024, K=2048)
        gemm_wide<1, 0, 4><<<256, 512, 0, stream>>>(
            align_h, nullptr, 512LL * 2048, encT, 1024LL * 2048,
            ctx, nullptr, nullptr, 512LL * 1024, 512, 1024, 2048);
    } else {
        // round-1 fallback (needs 32 MiB ws)
        float* dproj = (float*)d_ws;
        gemm_bt_x3<<<dim3(8, 64, 1), 256, 0, stream>>>(
            dec, 0, W, 0, dproj, 0, 8192, 1024, 1024);
        gemm_bt_x3<<<dim3(16, 4, 16), 256, 0, stream>>>(
            dproj, 512LL * 1024, enc, 2048LL * 1024, align, 512LL * 2048, 512, 2048, 1024);
        softmax_rows<<<8192, 256, 0, stream>>>(align, nullptr);
        gemm_nn_bf16<<<dim3(8, 4, 16), 256, 0, stream>>>(
            align, 512LL * 2048, enc, 2048LL * 1024, ctx, 512LL * 1024, 512, 1024, 2048);
    }
}

// Round 13
// 265.019 us; speedup vs baseline: 1.0323x; 1.0065x over previous
//
#include <hip/hip_runtime.h>
#include <hip/hip_bf16.h>

// LuongAttention: B=16, Tq=512, Tk=2048, D=1024 (fp32 in/out)
// Fast path (ws >= 160 MiB), all-fp16 planes:
//   P0: split_enc_T: enc -> enc_h (fp16) + encT (fp16, transposed); dec h/l; W h
//   K1: dproj_h/l = split(dec @ W_h^T)   gemm_wide<2,1,4>  (128x256, 2-ph dbuf)
//   K2: score = (dproj_h+l) @ enc_h^T    gemm_wide<2,0,8>  (256x256, 2-ph dbuf)
//   K3: softmax in place + fp16 copy (align_h)
//   K4: ctx = align_h @ encT^T           gemm_wide<1,0,4>  (128x256, 2-ph dbuf)
// fp16-x2 decomposition: A split into fp16 hi+lo (~22 bits), B single fp16.
// r13: split_enc_T rebuilt with in-register 4x4 transpose: 4x b64 LDS writes +
// 2x b128 LDS reads per thread (was ~32 scalar u16 ops, issue-bound at 78 us).
// Schedule variants all regressed vs this GEMM config: drain-0 phase-split
// (r6), 32x32 frags (r7), 3-buf counted-vmcnt (r8), small-tile 2-blk/CU (r11).
// wa_bias cancels in softmax -> skipped. Fallback (<160 MiB): r1 bf16 kernels.

typedef float f32x4 __attribute__((ext_vector_type(4)));
typedef _Float16 f16x8 __attribute__((ext_vector_type(8)));
typedef __bf16 bf16x8 __attribute__((ext_vector_type(8)));
typedef unsigned short u16x4 __attribute__((ext_vector_type(4)));
typedef unsigned short u16x8 __attribute__((ext_vector_type(8)));

__device__ inline unsigned short h_bits(_Float16 h) {
    union { _Float16 h; unsigned short u; } v; v.h = h; return v.u;
}
// returns hi fp16 bits in [15:0], lo fp16 bits in [31:16]
__device__ inline unsigned int split_f16(float x) {
    _Float16 h = (_Float16)x;
    _Float16 l = (_Float16)(x - (float)h);
    return (unsigned int)h_bits(h) | ((unsigned int)h_bits(l) << 16);
}

__device__ inline void gload16(const void* g, const void* l) {
    __builtin_amdgcn_global_load_lds(
        (const __attribute__((address_space(1))) unsigned int*)g,
        (__attribute__((address_space(3))) unsigned int*)l, 16, 0, 0);
}

// ---------------- P0: fp32 -> fp16 hi(/lo) split (elementwise) --------------
__global__ __launch_bounds__(256)
void splitf16(const float* __restrict__ x, unsigned short* __restrict__ ho,
              unsigned short* __restrict__ lo, int n8)
{
    int i = blockIdx.x * 256 + threadIdx.x;
    if (i >= n8) return;
    const f32x4* xp = reinterpret_cast<const f32x4*>(x + (size_t)i * 8);
    f32x4 v0 = xp[0], v1 = xp[1];
    u16x8 h, l;
#pragma unroll
    for (int j = 0; j < 4; ++j) {
        unsigned int p0 = split_f16(v0[j]);
        unsigned int p1 = split_f16(v1[j]);
        h[j] = (unsigned short)p0;      l[j] = (unsigned short)(p0 >> 16);
        h[4 + j] = (unsigned short)p1;  l[4 + j] = (unsigned short)(p1 >> 16);
    }
    *reinterpret_cast<u16x8*>(ho + (size_t)i * 8) = h;
    if (lo) *reinterpret_cast<u16x8*>(lo + (size_t)i * 8) = l;
}

// ---- P0 fused: enc fp32 -> enc_h (fp16 row-major) + encT (fp16 transposed) -
// enc [16][2048][1024]; encT [16][1024][2048]. 64x64 tiles, 256 threads.
// In-register 4x4 transpose: thread (bk,bd) owns input rows kb+4bk..+3, cols
// db+4bd..+3. LDS stride 72 u16: row-chunk reads are 16B-aligned (b128);
// transposed writes are b64. LDS ops/thread: 4 write + 2 read (wide).
__global__ __launch_bounds__(256)
void split_enc_T(const float* __restrict__ enc, unsigned short* __restrict__ eh,
                 unsigned short* __restrict__ eT)
{
    __shared__ unsigned short t[64][72];   // [d][k]
    const int b = blockIdx.z;
    const int kb = blockIdx.x * 64;   // Tk
    const int db = blockIdx.y * 64;   // D
    const int bk = threadIdx.x >> 4;        // 0..15
    const int bd = threadIdx.x & 15;        // 0..15

    const float* ip = enc + ((size_t)b * 2048 + kb + bk * 4) * 1024 + db + bd * 4;
    unsigned short* ehp = eh + ((size_t)b * 2048 + kb + bk * 4) * 1024 + db + bd * 4;

    u16x4 h[4];
#pragma unroll
    for (int r = 0; r < 4; ++r) {
        f32x4 v = *reinterpret_cast<const f32x4*>(ip + (size_t)r * 1024);
        u16x4 hr;
#pragma unroll
        for (int j = 0; j < 4; ++j) hr[j] = h_bits((_Float16)v[j]);
        h[r] = hr;
        *reinterpret_cast<u16x4*>(ehp + (size_t)r * 1024) = hr;
    }
    // 4x4 in-register transpose -> b64 LDS writes
#pragma unroll
    for (int j = 0; j < 4; ++j) {
        u16x4 w;
        w[0] = h[0][j]; w[1] = h[1][j]; w[2] = h[2][j]; w[3] = h[3][j];
        *reinterpret_cast<u16x4*>(&t[bd * 4 + j][bk * 4]) = w;
    }
    __syncthreads();
    const int d = threadIdx.x >> 2;   // 0..63 (D within tile)
    const int ch = threadIdx.x & 3;   // 16-u16 chunk along k
    u16x8 w0 = *reinterpret_cast<const u16x8*>(&t[d][ch * 16]);      // b128
    u16x8 w1 = *reinterpret_cast<const u16x8*>(&t[d][ch * 16 + 8]);  // b128
    unsigned short* op = eT + ((size_t)b * 1024 + db + d) * 2048 + kb + ch * 16;
    *reinterpret_cast<u16x8*>(op) = w0;
    *reinterpret_cast<u16x8*>(op + 8) = w1;
}

// ========== wide BT GEMM, fp16, 16x16x32 MFMA, 2-phase dbuf (r5 schedule) ===
// C = (Ah[+Al]) @ Bh^T. A planes [M,K], B plane [N,K] fp16, K%32==0.
// BM=32*AM, BN=256, BK=32, 8 waves (2x4), wave-tile (16*AM)x64, acc[AM][4].
// Row-plane list: rp in [0,BM) = Ah rows, [BM,BM*APL) = Al rows,
// [RA, RA+256) = Bh rows. LDS rows 64B, phys chunk = (kc+(rp>>1))&3
// (conflict-free, measured r4/r5). Linear LDS dest (gload_lds) + pre-swizzled
// global src. 2-phase: stage(next buf) issued BEFORE compute(cur), one
// __syncthreads per K-tile. Grid: 1D nwg (nwg%8==0), XCD-swizzled, m-fastest.
// OUTMODE 0: fp32 C. OUTMODE 1: fp16 hi/lo split -> Ch, Cl.
// C/D layout [HW-verified]: col = lane&15, row = (lane>>4)*4 + j.
template<int APL, int OUTMODE, int AM>
__global__ __launch_bounds__(512, 2)
void gemm_wide(const unsigned short* __restrict__ Ah, const unsigned short* __restrict__ Al,
               long long sA,
               const unsigned short* __restrict__ Bh, long long sB,
               float* __restrict__ C, unsigned short* __restrict__ Ch,
               unsigned short* __restrict__ Cl, long long sC,
               int M, int N, int K)
{
    constexpr int BM  = 32 * AM;
    constexpr int RA  = BM * APL;                 // A row-planes
    constexpr int TOT = RA + 256;                 // + B row-planes
    constexpr int NI  = TOT / 128;                // gload16 per thread per tile
    constexpr int BUF = TOT * 32;                 // u16 elems per buffer
    __shared__ unsigned short smem[2 * BUF];

    const int tid = threadIdx.x, lane = tid & 63, wave = tid >> 6;

    // XCD swizzle + batch decode (m-fastest)
    const int nwg = gridDim.x;
    int orig = (blockIdx.x & 7) * (nwg >> 3) + (blockIdx.x >> 3);
    const int mb = M / BM, nb = N >> 8, bpb = mb * nb;
    const int z = orig / bpb, rem = orig - z * bpb;
    const int bm = (rem % mb) * BM, bn = (rem / mb) << 8;

    Ah += (size_t)z * sA; Bh += (size_t)z * sB;
    if (APL == 2) Al += (size_t)z * sA;

    // staging geometry: slot c = i*512+tid -> rp = c>>2, phys slot s = c&3
    // holds global chunk g = (s - (rp>>1)) & 3.
    const unsigned short* src[NI];
    int dst[NI];
#pragma unroll
    for (int i = 0; i < NI; ++i) {
        int c = i * 512 + tid, rp = c >> 2, s = c & 3;
        int g = (s + 4 - ((rp >> 1) & 3)) & 3;
        const unsigned short* bp;
        if (rp < BM)                    bp = Ah + (size_t)(bm + rp) * K;
        else if (APL == 2 && rp < RA)   bp = Al + (size_t)(bm + rp - BM) * K;
        else                            bp = Bh + (size_t)(bn + rp - RA) * K;
        src[i] = bp + g * 8;
        dst[i] = rp * 32 + s * 8;
    }

    const int kcL = lane >> 4, fr = lane & 15;
    const int wrow = (wave >> 2) * (16 * AM);
    const int wcol = (wave & 3) * 64;

    f32x4 acc[AM][4] = {};
    const int nt = K >> 5;
    int cur = 0;

    {   // prologue: stage K-tile 0 into buf 0
#pragma unroll
        for (int i = 0; i < NI; ++i) gload16(src[i], smem + dst[i]);
    }
    __syncthreads();

    for (int t = 0; t < nt; ++t) {
        if (t + 1 < nt) {   // issue next-tile stage BEFORE compute (2-phase)
            const int kt = (t + 1) << 5;
            unsigned short* bx = smem + (cur ^ 1) * BUF;
#pragma unroll
            for (int i = 0; i < NI; ++i) gload16(src[i] + kt, bx + dst[i]);
        }
        const unsigned short* base = smem + cur * BUF;
        f16x8 bhf[4];
#pragma unroll
        for (int n = 0; n < 4; ++n) {
            int rp = RA + wcol + n * 16 + fr;
            bhf[n] = *reinterpret_cast<const f16x8*>(base + rp * 32 + (((kcL + (rp >> 1)) & 3) << 3));
        }
#pragma unroll
        for (int m = 0; m < AM; ++m) {
            int ra = wrow + m * 16 + fr;
            f16x8 ah = *reinterpret_cast<const f16x8*>(base + ra * 32 + (((kcL + (ra >> 1)) & 3) << 3));
            f16x8 al;
            if (APL == 2) {
                int rp = BM + ra;
                al = *reinterpret_cast<const f16x8*>(base + rp * 32 + (((kcL + (rp >> 1)) & 3) << 3));
            }
#pragma unroll
            for (int n = 0; n < 4; ++n) {
                acc[m][n] = __builtin_amdgcn_mfma_f32_16x16x32_f16(ah, bhf[n], acc[m][n], 0, 0, 0);
                if (APL == 2)
                    acc[m][n] = __builtin_amdgcn_mfma_f32_16x16x32_f16(al, bhf[n], acc[m][n], 0, 0, 0);
            }
        }
        __syncthreads();   // drains vmcnt: next buf staged; reads of cur done
        cur ^= 1;
    }

    // C/D layout: col = lane&15, row = (lane>>4)*4 + j  [HW-verified]
    if constexpr (OUTMODE == 0) {
        float* Cz = C + (size_t)z * sC;
#pragma unroll
        for (int m = 0; m < AM; ++m)
#pragma unroll
            for (int j = 0; j < 4; ++j) {
                int grow = bm + wrow + m * 16 + (lane >> 4) * 4 + j;
                float* cr = Cz + (size_t)grow * N + bn + wcol + fr;
#pragma unroll
                for (int n = 0; n < 4; ++n) cr[n * 16] = acc[m][n][j];
            }
    } else {
        unsigned short* Chz = Ch + (size_t)z * sC;
        unsigned short* Clz = Cl + (size_t)z * sC;
#pragma unroll
        for (int m = 0; m < AM; ++m)
#pragma unroll
            for (int j = 0; j < 4; ++j) {
                int grow = bm + wrow + m * 16 + (lane >> 4) * 4 + j;
                size_t rb = (size_t)grow * N + bn + wcol + fr;
#pragma unroll
                for (int n = 0; n < 4; ++n) {
                    unsigned int p = split_f16(acc[m][n][j]);
                    Chz[rb + n * 16] = (unsigned short)p;
                    Clz[rb + n * 16] = (unsigned short)(p >> 16);
                }
            }
    }
}

// ---------------- softmax rows (2048 cols) + optional fp16 copy -------------
__global__ __launch_bounds__(256)
void softmax_rows(float* __restrict__ P, unsigned short* __restrict__ alh)
{
    __shared__ float redm[4], reds[4];
    float* p = P + (size_t)blockIdx.x * 2048;
    const int tid = threadIdx.x, lane = tid & 63, wave = tid >> 6;

    f32x4 v0 = *reinterpret_cast<const f32x4*>(p + tid * 4);
    f32x4 v1 = *reinterpret_cast<const f32x4*>(p + 1024 + tid * 4);

    float mx = fmaxf(fmaxf(fmaxf(v0[0], v0[1]), fmaxf(v0[2], v0[3])),
                     fmaxf(fmaxf(v1[0], v1[1]), fmaxf(v1[2], v1[3])));
#pragma unroll
    for (int o = 32; o; o >>= 1) mx = fmaxf(mx, __shfl_xor(mx, o));
    if (lane == 0) redm[wave] = mx;
    __syncthreads();
    mx = fmaxf(fmaxf(redm[0], redm[1]), fmaxf(redm[2], redm[3]));

    float s = 0.f;
#pragma unroll
    for (int j = 0; j < 4; ++j) { v0[j] = __expf(v0[j] - mx); s += v0[j]; }
#pragma unroll
    for (int j = 0; j < 4; ++j) { v1[j] = __expf(v1[j] - mx); s += v1[j]; }
#pragma unroll
    for (int o = 32; o; o >>= 1) s += __shfl_xor(s, o);
    if (lane == 0) reds[wave] = s;
    __syncthreads();
    s = reds[0] + reds[1] + reds[2] + reds[3];

    const float inv = 1.0f / s;
#pragma unroll
    for (int j = 0; j < 4; ++j) { v0[j] *= inv; v1[j] *= inv; }
    *reinterpret_cast<f32x4*>(p + tid * 4) = v0;
    *reinterpret_cast<f32x4*>(p + 1024 + tid * 4) = v1;

    if (alh) {
        unsigned short* ab = alh + (size_t)blockIdx.x * 2048;
        u16x4 h0, h1;
#pragma unroll
        for (int j = 0; j < 4; ++j) {
            h0[j] = h_bits((_Float16)v0[j]);
            h1[j] = h_bits((_Float16)v1[j]);
        }
        *reinterpret_cast<u16x4*>(ab + tid * 4) = h0;
        *reinterpret_cast<u16x4*>(ab + 1024 + tid * 4) = h1;
    }
}

// ======================= round-1 fallback kernels (bf16) ====================
__device__ inline unsigned short f2bf(float f) {
    union { float f; unsigned int u; } v; v.f = f;
    unsigned int r = v.u + 0x7fffu + ((v.u >> 16) & 1u);
    return (unsigned short)(r >> 16);
}
__device__ inline float bf2f(unsigned short h) {
    union { unsigned int u; float f; } v; v.u = ((unsigned int)h) << 16; return v.f;
}
__device__ inline int tile_byte(int row, int kElem) {
    int chunk = kElem >> 3;
    return row * 128 + ((chunk ^ (row & 7)) << 4) + ((kElem & 7) << 1);
}

__global__ __launch_bounds__(256, 2)
void gemm_bt_x3(const float* __restrict__ A, long long sA,
                const float* __restrict__ Bt, long long sB,
                float* __restrict__ C, long long sC,
                int M, int N, int K)
{
    __shared__ unsigned short Ah[128 * 64], Al[128 * 64];
    __shared__ unsigned short Bh[128 * 64], Bl[128 * 64];

    const int tid = threadIdx.x, lane = tid & 63, wave = tid >> 6;
    const int wr = (wave >> 1) * 64, wc = (wave & 1) * 64;
    const int bm = blockIdx.y * 128, bn = blockIdx.x * 128;
    A += (size_t)blockIdx.z * sA;
    Bt += (size_t)blockIdx.z * sB;
    C += (size_t)blockIdx.z * sC;

    f32x4 acc[4][4] = {};

    for (int kt = 0; kt < K; kt += 64) {
#pragma unroll
        for (int i = 0; i < 8; ++i) {
            int idx = tid + i * 256;
            int row = idx >> 4, f4 = idx & 15;
            f32x4 va = *reinterpret_cast<const f32x4*>(A + (size_t)(bm + row) * K + kt + f4 * 4);
            f32x4 vb = *reinterpret_cast<const f32x4*>(Bt + (size_t)(bn + row) * K + kt + f4 * 4);
            u16x4 ah, al, bh, bl;
#pragma unroll
            for (int j = 0; j < 4; ++j) {
                unsigned short h = f2bf(va[j]);
                ah[j] = h; al[j] = f2bf(va[j] - bf2f(h));
                h = f2bf(vb[j]);
                bh[j] = h; bl[j] = f2bf(vb[j] - bf2f(h));
            }
            int off = tile_byte(row, f4 * 4);
            *reinterpret_cast<u16x4*>((char*)Ah + off) = ah;
            *reinterpret_cast<u16x4*>((char*)Al + off) = al;
            *reinterpret_cast<u16x4*>((char*)Bh + off) = bh;
            *reinterpret_cast<u16x4*>((char*)Bl + off) = bl;
        }
        __syncthreads();
#pragma unroll
        for (int kk = 0; kk < 2; ++kk) {
            bf16x8 a_h[4], a_l[4], b_h[4], b_l[4];
            const int kbase = kk * 32 + (lane >> 4) * 8;
#pragma unroll
            for (int m = 0; m < 4; ++m) {
                int off = tile_byte(wr + m * 16 + (lane & 15), kbase);
                a_h[m] = *reinterpret_cast<const bf16x8*>((char*)Ah + off);
                a_l[m] = *reinterpret_cast<const bf16x8*>((char*)Al + off);
            }
#pragma unroll
            for (int n = 0; n < 4; ++n) {
                int off = tile_byte(wc + n * 16 + (lane & 15), kbase);
                b_h[n] = *reinterpret_cast<const bf16x8*>((char*)Bh + off);
                b_l[n] = *reinterpret_cast<const bf16x8*>((char*)Bl + off);
            }
#pragma unroll
            for (int m = 0; m < 4; ++m)
#pragma unroll
                for (int n = 0; n < 4; ++n) {
                    acc[m][n] = __builtin_amdgcn_mfma_f32_16x16x32_bf16(a_h[m], b_h[n], acc[m][n], 0, 0, 0);
                    acc[m][n] = __builtin_amdgcn_mfma_f32_16x16x32_bf16(a_h[m], b_l[n], acc[m][n], 0, 0, 0);
                    acc[m][n] = __builtin_amdgcn_mfma_f32_16x16x32_bf16(a_l[m], b_h[n], acc[m][n], 0, 0, 0);
                }
        }
        __syncthreads();
    }
#pragma unroll
    for (int m = 0; m < 4; ++m)
#pragma unroll
        for (int j = 0; j < 4; ++j) {
            int grow = bm + wr + m * 16 + (lane >> 4) * 4 + j;
            float* cr = C + (size_t)grow * N + bn + wc + (lane & 15);
#pragma unroll
            for (int n = 0; n < 4; ++n) cr[n * 16] = acc[m][n][j];
        }
}

__global__ __launch_bounds__(256, 2)
void gemm_nn_bf16(const float* __restrict__ A, long long sA,
                  const float* __restrict__ Bn, long long sB,
                  float* __restrict__ C, long long sC,
                  int M, int N, int K)
{
    __shared__ unsigned short As[128 * 64];
    __shared__ unsigned short Bs[64 * 130];

    const int tid = threadIdx.x, lane = tid & 63, wave = tid >> 6;
    const int wr = (wave >> 1) * 64, wc = (wave & 1) * 64;
    const int bm = blockIdx.y * 128, bn = blockIdx.x * 128;
    A += (size_t)blockIdx.z * sA;
    Bn += (size_t)blockIdx.z * sB;
    C += (size_t)blockIdx.z * sC;

    f32x4 acc[4][4] = {};

    for (int kt = 0; kt < K; kt += 64) {
#pragma unroll
        for (int i = 0; i < 8; ++i) {
            int idx = tid + i * 256;
            int row = idx >> 4, f4 = idx & 15;
            f32x4 va = *reinterpret_cast<const f32x4*>(A + (size_t)(bm + row) * K + kt + f4 * 4);
            u16x4 h;
#pragma unroll
            for (int j = 0; j < 4; ++j) h[j] = f2bf(va[j]);
            *reinterpret_cast<u16x4*>((char*)As + tile_byte(row, f4 * 4)) = h;
        }
#pragma unroll
        for (int i = 0; i < 8; ++i) {
            int idx = tid + i * 256;
            int krow = idx >> 5, f4 = idx & 31;
            f32x4 vb = *reinterpret_cast<const f32x4*>(Bn + (size_t)(kt + krow) * N + bn + f4 * 4);
            unsigned int p0 = (unsigned int)f2bf(vb[0]) | ((unsigned int)f2bf(vb[1]) << 16);
            unsigned int p1 = (unsigned int)f2bf(vb[2]) | ((unsigned int)f2bf(vb[3]) << 16);
            unsigned int* bp = reinterpret_cast<unsigned int*>(&Bs[krow * 130 + f4 * 4]);
            bp[0] = p0; bp[1] = p1;
        }
        __syncthreads();
#pragma unroll
        for (int kk = 0; kk < 2; ++kk) {
            bf16x8 a[4], b[4];
            const int kbase = kk * 32 + (lane >> 4) * 8;
#pragma unroll
            for (int m = 0; m < 4; ++m)
                a[m] = *reinterpret_cast<const bf16x8*>((char*)As + tile_byte(wr + m * 16 + (lane & 15), kbase));
#pragma unroll
            for (int n = 0; n < 4; ++n) {
                int col = wc + n * 16 + (lane & 15);
                union { unsigned short u[8]; bf16x8 v; } t;
#pragma unroll
                for (int j = 0; j < 8; ++j) t.u[j] = Bs[(kbase + j) * 130 + col];
                b[n] = t.v;
            }
#pragma unroll
            for (int m = 0; m < 4; ++m)
#pragma unroll
                for (int n = 0; n < 4; ++n)
                    acc[m][n] = __builtin_amdgcn_mfma_f32_16x16x32_bf16(a[m], b[n], acc[m][n], 0, 0, 0);
        }
        __syncthreads();
    }
#pragma unroll
    for (int m = 0; m < 4; ++m)
#pragma unroll
        for (int j = 0; j < 4; ++j) {
            int grow = bm + wr + m * 16 + (lane >> 4) * 4 + j;
            float* cr = C + (size_t)grow * N + bn + wc + (lane & 15);
#pragma unroll
            for (int n = 0; n < 4; ++n) cr[n * 16] = acc[m][n][j];
        }
}

// ============================================================================
extern "C" void kernel_launch(void* const* d_in, const int* in_sizes, int n_in,
                              void* d_out, int out_size, void* d_ws, size_t ws_size,
                              hipStream_t stream)
{
    (void)in_sizes; (void)n_in; (void)out_size;
    const float* dec = (const float*)d_in[0];   // [16,512,1024]
    const float* enc = (const float*)d_in[1];   // [16,2048,1024]
    const float* W   = (const float*)d_in[2];   // [1024,1024]

    float* ctx   = (float*)d_out;                            // [16,512,1024]
    float* align = (float*)d_out + (size_t)16 * 512 * 1024;  // [16,512,2048]

    const size_t NEED_FAST = 160ULL * 1048576ULL;  // enc_h + encT + align_h

    if (ws_size >= NEED_FAST) {
        unsigned short* enc_h   = (unsigned short*)d_ws;             // 64 MiB
        unsigned short* encT    = enc_h + 33554432ULL;               // 64 MiB
        unsigned short* align_h = encT + 33554432ULL;                // 32 MiB
        unsigned short* dproj_h = (unsigned short*)d_out;            // ctx region (dead until K4)
        unsigned short* dproj_l = dproj_h + 8388608ULL;
        unsigned short* dec_h   = (unsigned short*)align;            // align region (dead until K2)
        unsigned short* dec_l   = dec_h + 8388608ULL;
        unsigned short* W_h     = dec_l + 8388608ULL;

        // P0: enc -> enc_h + encT (fused transpose); dec h/l; W h only
        split_enc_T<<<dim3(32, 16, 16), 256, 0, stream>>>(enc, enc_h, encT);
        splitf16<<<4096, 256, 0, stream>>>(dec, dec_h, dec_l, 1048576);
        splitf16<<<512, 256, 0, stream>>>(W, W_h, nullptr, 131072);

        // K1: dproj = dec @ W_h^T  (M=8192, N=1024, K=1024) -> fp16 h/l planes
        gemm_wide<2, 1, 4><<<256, 512, 0, stream>>>(
            dec_h, dec_l, 0, W_h, 0,
            nullptr, dproj_h, dproj_l, 0, 8192, 1024, 1024);

        // K2: score = dproj @ enc_h^T per batch (M=512, N=2048, K=1024) -> align
        gemm_wide<2, 0, 8><<<256, 512, 0, stream>>>(
            dproj_h, dproj_l, 512LL * 1024, enc_h, 2048LL * 1024,
            align, nullptr, nullptr, 512LL * 2048, 512, 2048, 1024);

        // K3: softmax + fp16 copy
        softmax_rows<<<8192, 256, 0, stream>>>(align, align_h);

        // K4: ctx = align_h @ encT^T per batch (M=512, N=1024, K=2048)
        gemm_wide<1, 0, 4><<<256, 512, 0, stream>>>(
            align_h, nullptr, 512LL * 2048, encT, 1024LL * 2048,
            ctx, nullptr, nullptr, 512LL * 1024, 512, 1024, 2048);
    } else {
        // round-1 fallback (needs 32 MiB ws)
        float* dproj = (float*)d_ws;
        gemm_bt_x3<<<dim3(8, 64, 1), 256, 0, stream>>>(
            dec, 0, W, 0, dproj, 0, 8192, 1024, 1024);
        gemm_bt_x3<<<dim3(16, 4, 16), 256, 0, stream>>>(
            dproj, 512LL * 1024, enc, 2048LL * 1024, align, 512LL * 2048, 512, 2048, 1024);
        softmax_rows<<<8192, 256, 0, stream>>>(align, nullptr);
        gemm_nn_bf16<<<dim3(8, 4, 16), 256, 0, stream>>>(
            align, 512LL * 2048, enc, 2048LL * 1024, ctx, 512LL * 1024, 512, 1024, 2048);
    }
}

// Round 14
// 263.745 us; speedup vs baseline: 1.0373x; 1.0048x over previous
//
#include <hip/hip_runtime.h>
#include <hip/hip_bf16.h>

// LuongAttention: B=16, Tq=512, Tk=2048, D=1024 (fp32 in/out)
// Fast path (ws >= 160 MiB), all-fp16 planes:
//   P0: split_enc_T: enc -> enc_h (fp16) + encT (fp16, transposed); dec h/l; W h
//   K1: dproj_h/l = split(dec @ W_h^T)   gemm_wide<2,1,4>  (128x256, 2-ph dbuf)
//   K2: score = (dproj_h+l) @ enc_h^T    gemm_k2_3buf      (256x256, 3-buf
//       counted-vmcnt: stage t+2 in flight across barrier, wait vmcnt(6))
//   K3: softmax in place + fp16 copy (align_h)
//   K4: ctx = align_h @ encT^T           gemm_wide<1,0,4>  (128x256, 2-ph dbuf)
// fp16-x2: A split into fp16 hi+lo (~22 bits), B single fp16. r14: K2 moves
// to 3-buffer counted-vmcnt at BM=256 (possible only with fp16's 48KB buffer;
// r8's 3-buf failure was confounded by BM=128 tile shrink). K1/K4 stay 2-ph.
// wa_bias cancels in softmax -> skipped. Fallback (<160 MiB): r1 bf16 kernels.

typedef float f32x4 __attribute__((ext_vector_type(4)));
typedef _Float16 f16x8 __attribute__((ext_vector_type(8)));
typedef __bf16 bf16x8 __attribute__((ext_vector_type(8)));
typedef unsigned short u16x4 __attribute__((ext_vector_type(4)));
typedef unsigned short u16x8 __attribute__((ext_vector_type(8)));

__device__ inline unsigned short h_bits(_Float16 h) {
    union { _Float16 h; unsigned short u; } v; v.h = h; return v.u;
}
// returns hi fp16 bits in [15:0], lo fp16 bits in [31:16]
__device__ inline unsigned int split_f16(float x) {
    _Float16 h = (_Float16)x;
    _Float16 l = (_Float16)(x - (float)h);
    return (unsigned int)h_bits(h) | ((unsigned int)h_bits(l) << 16);
}

__device__ inline void gload16(const void* g, const void* l) {
    __builtin_amdgcn_global_load_lds(
        (const __attribute__((address_space(1))) unsigned int*)g,
        (__attribute__((address_space(3))) unsigned int*)l, 16, 0, 0);
}

// ---------------- P0: fp32 -> fp16 hi(/lo) split (elementwise) --------------
__global__ __launch_bounds__(256)
void splitf16(const float* __restrict__ x, unsigned short* __restrict__ ho,
              unsigned short* __restrict__ lo, int n8)
{
    int i = blockIdx.x * 256 + threadIdx.x;
    if (i >= n8) return;
    const f32x4* xp = reinterpret_cast<const f32x4*>(x + (size_t)i * 8);
    f32x4 v0 = xp[0], v1 = xp[1];
    u16x8 h, l;
#pragma unroll
    for (int j = 0; j < 4; ++j) {
        unsigned int p0 = split_f16(v0[j]);
        unsigned int p1 = split_f16(v1[j]);
        h[j] = (unsigned short)p0;      l[j] = (unsigned short)(p0 >> 16);
        h[4 + j] = (unsigned short)p1;  l[4 + j] = (unsigned short)(p1 >> 16);
    }
    *reinterpret_cast<u16x8*>(ho + (size_t)i * 8) = h;
    if (lo) *reinterpret_cast<u16x8*>(lo + (size_t)i * 8) = l;
}

// ---- P0 fused: enc fp32 -> enc_h (fp16 row-major) + encT (fp16 transposed) -
__global__ __launch_bounds__(256)
void split_enc_T(const float* __restrict__ enc, unsigned short* __restrict__ eh,
                 unsigned short* __restrict__ eT)
{
    __shared__ unsigned short t[64][72];   // [d][k]
    const int b = blockIdx.z;
    const int kb = blockIdx.x * 64;   // Tk
    const int db = blockIdx.y * 64;   // D
    const int bk = threadIdx.x >> 4;        // 0..15
    const int bd = threadIdx.x & 15;        // 0..15

    const float* ip = enc + ((size_t)b * 2048 + kb + bk * 4) * 1024 + db + bd * 4;
    unsigned short* ehp = eh + ((size_t)b * 2048 + kb + bk * 4) * 1024 + db + bd * 4;

    u16x4 h[4];
#pragma unroll
    for (int r = 0; r < 4; ++r) {
        f32x4 v = *reinterpret_cast<const f32x4*>(ip + (size_t)r * 1024);
        u16x4 hr;
#pragma unroll
        for (int j = 0; j < 4; ++j) hr[j] = h_bits((_Float16)v[j]);
        h[r] = hr;
        *reinterpret_cast<u16x4*>(ehp + (size_t)r * 1024) = hr;
    }
#pragma unroll
    for (int j = 0; j < 4; ++j) {
        u16x4 w;
        w[0] = h[0][j]; w[1] = h[1][j]; w[2] = h[2][j]; w[3] = h[3][j];
        *reinterpret_cast<u16x4*>(&t[bd * 4 + j][bk * 4]) = w;
    }
    __syncthreads();
    const int d = threadIdx.x >> 2;
    const int ch = threadIdx.x & 3;
    u16x8 w0 = *reinterpret_cast<const u16x8*>(&t[d][ch * 16]);
    u16x8 w1 = *reinterpret_cast<const u16x8*>(&t[d][ch * 16 + 8]);
    unsigned short* op = eT + ((size_t)b * 1024 + db + d) * 2048 + kb + ch * 16;
    *reinterpret_cast<u16x8*>(op) = w0;
    *reinterpret_cast<u16x8*>(op + 8) = w1;
}

// ========== K2: 256x256 fp16-x2, 3-buffer counted-vmcnt pipeline ============
// C = (Ah+Al) @ Bh^T, A planes [M,K], B [N,K] fp16. BM=256, BN=256, BK=32,
// 8 waves, wave-tile 128x64, acc[8][4]. Same LDS layout/swizzle as gemm_wide
// (rows 64B, phys chunk=(kc+(rp>>1))&3, conflict-free). 3 buffers (144 KiB):
// iter t issues STAGE(t+2), computes buf[t%3], waits vmcnt(6) (t+1's 6 loads
// landed, t+2's stay IN FLIGHT across the raw s_barrier - T4 counted drain).
// Overwrite safety: buf[(t+2)%3] was computed at t-1; its ds_reads retired
// before the t-1 barrier. vmcnt completes in issue order (m135).
__global__ __launch_bounds__(512, 1)
void gemm_k2_3buf(const unsigned short* __restrict__ Ah, const unsigned short* __restrict__ Al,
                  long long sA,
                  const unsigned short* __restrict__ Bh, long long sB,
                  float* __restrict__ C, long long sC,
                  int M, int N, int K)
{
    constexpr int AM  = 8;
    constexpr int BM  = 256;
    constexpr int RA  = 512;                  // 2 A-planes x 256 rows
    constexpr int TOT = RA + 256;             // + B rows
    constexpr int NI  = TOT / 128;            // 6 gload16 per thread per tile
    constexpr int BUF = TOT * 32;             // 24576 u16 = 48 KiB
    __shared__ unsigned short smem[3 * BUF];  // 144 KiB

    const int tid = threadIdx.x, lane = tid & 63, wave = tid >> 6;

    const int nwg = gridDim.x;
    int orig = (blockIdx.x & 7) * (nwg >> 3) + (blockIdx.x >> 3);
    const int mb = M / BM, nb = N >> 8, bpb = mb * nb;
    const int z = orig / bpb, rem = orig - z * bpb;
    const int bm = (rem % mb) * BM, bn = (rem / mb) << 8;

    Ah += (size_t)z * sA; Al += (size_t)z * sA; Bh += (size_t)z * sB;

    const unsigned short* src[NI];
    int dst[NI];
#pragma unroll
    for (int i = 0; i < NI; ++i) {
        int c = i * 512 + tid, rp = c >> 2, s = c & 3;
        int g = (s + 4 - ((rp >> 1) & 3)) & 3;
        const unsigned short* bp;
        if (rp < BM)            bp = Ah + (size_t)(bm + rp) * K;
        else if (rp < RA)       bp = Al + (size_t)(bm + rp - BM) * K;
        else                    bp = Bh + (size_t)(bn + rp - RA) * K;
        src[i] = bp + g * 8;
        dst[i] = rp * 32 + s * 8;
    }

    const int kcL = lane >> 4, fr = lane & 15;
    const int wrow = (wave >> 2) * 128;
    const int wcol = (wave & 3) * 64;

    f32x4 acc[AM][4] = {};
    const int nt = K >> 5;   // 32

    auto STAGE = [&](int b3, int kt) {
        unsigned short* bx = smem + b3 * BUF;
#pragma unroll
        for (int i = 0; i < NI; ++i) gload16(src[i] + kt, bx + dst[i]);
    };

    // prologue: stage tiles 0,1; wait tile0 landed (tile1 in flight)
    STAGE(0, 0);
    if (nt > 1) { STAGE(1, 32); asm volatile("s_waitcnt vmcnt(6)" ::: "memory"); }
    else        { asm volatile("s_waitcnt vmcnt(0)" ::: "memory"); }
    __builtin_amdgcn_s_barrier();
    asm volatile("" ::: "memory");

    int cur = 0;
    for (int t = 0; t < nt; ++t) {
        if (t + 2 < nt) {
            int nb3 = cur + 2; if (nb3 >= 3) nb3 -= 3;
            STAGE(nb3, (t + 2) << 5);
        }
        const unsigned short* base = smem + cur * BUF;
        f16x8 bhf[4];
#pragma unroll
        for (int n = 0; n < 4; ++n) {
            int rp = RA + wcol + n * 16 + fr;
            bhf[n] = *reinterpret_cast<const f16x8*>(base + rp * 32 + (((kcL + (rp >> 1)) & 3) << 3));
        }
#pragma unroll
        for (int m = 0; m < AM; ++m) {
            int ra = wrow + m * 16 + fr;
            f16x8 ah = *reinterpret_cast<const f16x8*>(base + ra * 32 + (((kcL + (ra >> 1)) & 3) << 3));
            int rl = BM + ra;
            f16x8 al = *reinterpret_cast<const f16x8*>(base + rl * 32 + (((kcL + (rl >> 1)) & 3) << 3));
#pragma unroll
            for (int n = 0; n < 4; ++n) {
                acc[m][n] = __builtin_amdgcn_mfma_f32_16x16x32_f16(ah, bhf[n], acc[m][n], 0, 0, 0);
                acc[m][n] = __builtin_amdgcn_mfma_f32_16x16x32_f16(al, bhf[n], acc[m][n], 0, 0, 0);
            }
        }
        if (t + 1 < nt) {
            if (t + 2 < nt) asm volatile("s_waitcnt vmcnt(6)" ::: "memory");
            else            asm volatile("s_waitcnt vmcnt(0)" ::: "memory");
            __builtin_amdgcn_s_barrier();
            asm volatile("" ::: "memory");
        }
        ++cur; if (cur >= 3) cur = 0;
    }

    // C/D layout: col = lane&15, row = (lane>>4)*4 + j  [HW-verified]
    float* Cz = C + (size_t)z * sC;
#pragma unroll
    for (int m = 0; m < AM; ++m)
#pragma unroll
        for (int j = 0; j < 4; ++j) {
            int grow = bm + wrow + m * 16 + (lane >> 4) * 4 + j;
            float* cr = Cz + (size_t)grow * N + bn + wcol + fr;
#pragma unroll
            for (int n = 0; n < 4; ++n) cr[n * 16] = acc[m][n][j];
        }
}

// ========== wide BT GEMM, fp16, 16x16x32 MFMA, 2-phase dbuf (r5 schedule) ===
template<int APL, int OUTMODE, int AM>
__global__ __launch_bounds__(512, 2)
void gemm_wide(const unsigned short* __restrict__ Ah, const unsigned short* __restrict__ Al,
               long long sA,
               const unsigned short* __restrict__ Bh, long long sB,
               float* __restrict__ C, unsigned short* __restrict__ Ch,
               unsigned short* __restrict__ Cl, long long sC,
               int M, int N, int K)
{
    constexpr int BM  = 32 * AM;
    constexpr int RA  = BM * APL;
    constexpr int TOT = RA + 256;
    constexpr int NI  = TOT / 128;
    constexpr int BUF = TOT * 32;
    __shared__ unsigned short smem[2 * BUF];

    const int tid = threadIdx.x, lane = tid & 63, wave = tid >> 6;

    const int nwg = gridDim.x;
    int orig = (blockIdx.x & 7) * (nwg >> 3) + (blockIdx.x >> 3);
    const int mb = M / BM, nb = N >> 8, bpb = mb * nb;
    const int z = orig / bpb, rem = orig - z * bpb;
    const int bm = (rem % mb) * BM, bn = (rem / mb) << 8;

    Ah += (size_t)z * sA; Bh += (size_t)z * sB;
    if (APL == 2) Al += (size_t)z * sA;

    const unsigned short* src[NI];
    int dst[NI];
#pragma unroll
    for (int i = 0; i < NI; ++i) {
        int c = i * 512 + tid, rp = c >> 2, s = c & 3;
        int g = (s + 4 - ((rp >> 1) & 3)) & 3;
        const unsigned short* bp;
        if (rp < BM)                    bp = Ah + (size_t)(bm + rp) * K;
        else if (APL == 2 && rp < RA)   bp = Al + (size_t)(bm + rp - BM) * K;
        else                            bp = Bh + (size_t)(bn + rp - RA) * K;
        src[i] = bp + g * 8;
        dst[i] = rp * 32 + s * 8;
    }

    const int kcL = lane >> 4, fr = lane & 15;
    const int wrow = (wave >> 2) * (16 * AM);
    const int wcol = (wave & 3) * 64;

    f32x4 acc[AM][4] = {};
    const int nt = K >> 5;
    int cur = 0;

    {
#pragma unroll
        for (int i = 0; i < NI; ++i) gload16(src[i], smem + dst[i]);
    }
    __syncthreads();

    for (int t = 0; t < nt; ++t) {
        if (t + 1 < nt) {
            const int kt = (t + 1) << 5;
            unsigned short* bx = smem + (cur ^ 1) * BUF;
#pragma unroll
            for (int i = 0; i < NI; ++i) gload16(src[i] + kt, bx + dst[i]);
        }
        const unsigned short* base = smem + cur * BUF;
        f16x8 bhf[4];
#pragma unroll
        for (int n = 0; n < 4; ++n) {
            int rp = RA + wcol + n * 16 + fr;
            bhf[n] = *reinterpret_cast<const f16x8*>(base + rp * 32 + (((kcL + (rp >> 1)) & 3) << 3));
        }
#pragma unroll
        for (int m = 0; m < AM; ++m) {
            int ra = wrow + m * 16 + fr;
            f16x8 ah = *reinterpret_cast<const f16x8*>(base + ra * 32 + (((kcL + (ra >> 1)) & 3) << 3));
            f16x8 al;
            if (APL == 2) {
                int rp = BM + ra;
                al = *reinterpret_cast<const f16x8*>(base + rp * 32 + (((kcL + (rp >> 1)) & 3) << 3));
            }
#pragma unroll
            for (int n = 0; n < 4; ++n) {
                acc[m][n] = __builtin_amdgcn_mfma_f32_16x16x32_f16(ah, bhf[n], acc[m][n], 0, 0, 0);
                if (APL == 2)
                    acc[m][n] = __builtin_amdgcn_mfma_f32_16x16x32_f16(al, bhf[n], acc[m][n], 0, 0, 0);
            }
        }
        __syncthreads();
        cur ^= 1;
    }

    if constexpr (OUTMODE == 0) {
        float* Cz = C + (size_t)z * sC;
#pragma unroll
        for (int m = 0; m < AM; ++m)
#pragma unroll
            for (int j = 0; j < 4; ++j) {
                int grow = bm + wrow + m * 16 + (lane >> 4) * 4 + j;
                float* cr = Cz + (size_t)grow * N + bn + wcol + fr;
#pragma unroll
                for (int n = 0; n < 4; ++n) cr[n * 16] = acc[m][n][j];
            }
    } else {
        unsigned short* Chz = Ch + (size_t)z * sC;
        unsigned short* Clz = Cl + (size_t)z * sC;
#pragma unroll
        for (int m = 0; m < AM; ++m)
#pragma unroll
            for (int j = 0; j < 4; ++j) {
                int grow = bm + wrow + m * 16 + (lane >> 4) * 4 + j;
                size_t rb = (size_t)grow * N + bn + wcol + fr;
#pragma unroll
                for (int n = 0; n < 4; ++n) {
                    unsigned int p = split_f16(acc[m][n][j]);
                    Chz[rb + n * 16] = (unsigned short)p;
                    Clz[rb + n * 16] = (unsigned short)(p >> 16);
                }
            }
    }
}

// ---------------- softmax rows (2048 cols) + optional fp16 copy -------------
__global__ __launch_bounds__(256)
void softmax_rows(float* __restrict__ P, unsigned short* __restrict__ alh)
{
    __shared__ float redm[4], reds[4];
    float* p = P + (size_t)blockIdx.x * 2048;
    const int tid = threadIdx.x, lane = tid & 63, wave = tid >> 6;

    f32x4 v0 = *reinterpret_cast<const f32x4*>(p + tid * 4);
    f32x4 v1 = *reinterpret_cast<const f32x4*>(p + 1024 + tid * 4);

    float mx = fmaxf(fmaxf(fmaxf(v0[0], v0[1]), fmaxf(v0[2], v0[3])),
                     fmaxf(fmaxf(v1[0], v1[1]), fmaxf(v1[2], v1[3])));
#pragma unroll
    for (int o = 32; o; o >>= 1) mx = fmaxf(mx, __shfl_xor(mx, o));
    if (lane == 0) redm[wave] = mx;
    __syncthreads();
    mx = fmaxf(fmaxf(redm[0], redm[1]), fmaxf(redm[2], redm[3]));

    float s = 0.f;
#pragma unroll
    for (int j = 0; j < 4; ++j) { v0[j] = __expf(v0[j] - mx); s += v0[j]; }
#pragma unroll
    for (int j = 0; j < 4; ++j) { v1[j] = __expf(v1[j] - mx); s += v1[j]; }
#pragma unroll
    for (int o = 32; o; o >>= 1) s += __shfl_xor(s, o);
    if (lane == 0) reds[wave] = s;
    __syncthreads();
    s = reds[0] + reds[1] + reds[2] + reds[3];

    const float inv = 1.0f / s;
#pragma unroll
    for (int j = 0; j < 4; ++j) { v0[j] *= inv; v1[j] *= inv; }
    *reinterpret_cast<f32x4*>(p + tid * 4) = v0;
    *reinterpret_cast<f32x4*>(p + 1024 + tid * 4) = v1;

    if (alh) {
        unsigned short* ab = alh + (size_t)blockIdx.x * 2048;
        u16x4 h0, h1;
#pragma unroll
        for (int j = 0; j < 4; ++j) {
            h0[j] = h_bits((_Float16)v0[j]);
            h1[j] = h_bits((_Float16)v1[j]);
        }
        *reinterpret_cast<u16x4*>(ab + tid * 4) = h0;
        *reinterpret_cast<u16x4*>(ab + 1024 + tid * 4) = h1;
    }
}

// ======================= round-1 fallback kernels (bf16) ====================
__device__ inline unsigned short f2bf(float f) {
    union { float f; unsigned int u; } v; v.f = f;
    unsigned int r = v.u + 0x7fffu + ((v.u >> 16) & 1u);
    return (unsigned short)(r >> 16);
}
__device__ inline float bf2f(unsigned short h) {
    union { unsigned int u; float f; } v; v.u = ((unsigned int)h) << 16; return v.f;
}
__device__ inline int tile_byte(int row, int kElem) {
    int chunk = kElem >> 3;
    return row * 128 + ((chunk ^ (row & 7)) << 4) + ((kElem & 7) << 1);
}

__global__ __launch_bounds__(256, 2)
void gemm_bt_x3(const float* __restrict__ A, long long sA,
                const float* __restrict__ Bt, long long sB,
                float* __restrict__ C, long long sC,
                int M, int N, int K)
{
    __shared__ unsigned short Ah[128 * 64], Al[128 * 64];
    __shared__ unsigned short Bh[128 * 64], Bl[128 * 64];

    const int tid = threadIdx.x, lane = tid & 63, wave = tid >> 6;
    const int wr = (wave >> 1) * 64, wc = (wave & 1) * 64;
    const int bm = blockIdx.y * 128, bn = blockIdx.x * 128;
    A += (size_t)blockIdx.z * sA;
    Bt += (size_t)blockIdx.z * sB;
    C += (size_t)blockIdx.z * sC;

    f32x4 acc[4][4] = {};

    for (int kt = 0; kt < K; kt += 64) {
#pragma unroll
        for (int i = 0; i < 8; ++i) {
            int idx = tid + i * 256;
            int row = idx >> 4, f4 = idx & 15;
            f32x4 va = *reinterpret_cast<const f32x4*>(A + (size_t)(bm + row) * K + kt + f4 * 4);
            f32x4 vb = *reinterpret_cast<const f32x4*>(Bt + (size_t)(bn + row) * K + kt + f4 * 4);
            u16x4 ah, al, bh, bl;
#pragma unroll
            for (int j = 0; j < 4; ++j) {
                unsigned short h = f2bf(va[j]);
                ah[j] = h; al[j] = f2bf(va[j] - bf2f(h));
                h = f2bf(vb[j]);
                bh[j] = h; bl[j] = f2bf(vb[j] - bf2f(h));
            }
            int off = tile_byte(row, f4 * 4);
            *reinterpret_cast<u16x4*>((char*)Ah + off) = ah;
            *reinterpret_cast<u16x4*>((char*)Al + off) = al;
            *reinterpret_cast<u16x4*>((char*)Bh + off) = bh;
            *reinterpret_cast<u16x4*>((char*)Bl + off) = bl;
        }
        __syncthreads();
#pragma unroll
        for (int kk = 0; kk < 2; ++kk) {
            bf16x8 a_h[4], a_l[4], b_h[4], b_l[4];
            const int kbase = kk * 32 + (lane >> 4) * 8;
#pragma unroll
            for (int m = 0; m < 4; ++m) {
                int off = tile_byte(wr + m * 16 + (lane & 15), kbase);
                a_h[m] = *reinterpret_cast<const bf16x8*>((char*)Ah + off);
                a_l[m] = *reinterpret_cast<const bf16x8*>((char*)Al + off);
            }
#pragma unroll
            for (int n = 0; n < 4; ++n) {
                int off = tile_byte(wc + n * 16 + (lane & 15), kbase);
                b_h[n] = *reinterpret_cast<const bf16x8*>((char*)Bh + off);
                b_l[n] = *reinterpret_cast<const bf16x8*>((char*)Bl + off);
            }
#pragma unroll
            for (int m = 0; m < 4; ++m)
#pragma unroll
                for (int n = 0; n < 4; ++n) {
                    acc[m][n] = __builtin_amdgcn_mfma_f32_16x16x32_bf16(a_h[m], b_h[n], acc[m][n], 0, 0, 0);
                    acc[m][n] = __builtin_amdgcn_mfma_f32_16x16x32_bf16(a_h[m], b_l[n], acc[m][n], 0, 0, 0);
                    acc[m][n] = __builtin_amdgcn_mfma_f32_16x16x32_bf16(a_l[m], b_h[n], acc[m][n], 0, 0, 0);
                }
        }
        __syncthreads();
    }
#pragma unroll
    for (int m = 0; m < 4; ++m)
#pragma unroll
        for (int j = 0; j < 4; ++j) {
            int grow = bm + wr + m * 16 + (lane >> 4) * 4 + j;
            float* cr = C + (size_t)grow * N + bn + wc + (lane & 15);
#pragma unroll
            for (int n = 0; n < 4; ++n) cr[n * 16] = acc[m][n][j];
        }
}

__global__ __launch_bounds__(256, 2)
void gemm_nn_bf16(const float* __restrict__ A, long long sA,
                  const float* __restrict__ Bn, long long sB,
                  float* __restrict__ C, long long sC,
                  int M, int N, int K)
{
    __shared__ unsigned short As[128 * 64];
    __shared__ unsigned short Bs[64 * 130];

    const int tid = threadIdx.x, lane = tid & 63, wave = tid >> 6;
    const int wr = (wave >> 1) * 64, wc = (wave & 1) * 64;
    const int bm = blockIdx.y * 128, bn = blockIdx.x * 128;
    A += (size_t)blockIdx.z * sA;
    Bn += (size_t)blockIdx.z * sB;
    C += (size_t)blockIdx.z * sC;

    f32x4 acc[4][4] = {};

    for (int kt = 0; kt < K; kt += 64) {
#pragma unroll
        for (int i = 0; i < 8; ++i) {
            int idx = tid + i * 256;
            int row = idx >> 4, f4 = idx & 15;
            f32x4 va = *reinterpret_cast<const f32x4*>(A + (size_t)(bm + row) * K + kt + f4 * 4);
            u16x4 h;
#pragma unroll
            for (int j = 0; j < 4; ++j) h[j] = f2bf(va[j]);
            *reinterpret_cast<u16x4*>((char*)As + tile_byte(row, f4 * 4)) = h;
        }
#pragma unroll
        for (int i = 0; i < 8; ++i) {
            int idx = tid + i * 256;
            int krow = idx >> 5, f4 = idx & 31;
            f32x4 vb = *reinterpret_cast<const f32x4*>(Bn + (size_t)(kt + krow) * N + bn + f4 * 4);
            unsigned int p0 = (unsigned int)f2bf(vb[0]) | ((unsigned int)f2bf(vb[1]) << 16);
            unsigned int p1 = (unsigned int)f2bf(vb[2]) | ((unsigned int)f2bf(vb[3]) << 16);
            unsigned int* bp = reinterpret_cast<unsigned int*>(&Bs[krow * 130 + f4 * 4]);
            bp[0] = p0; bp[1] = p1;
        }
        __syncthreads();
#pragma unroll
        for (int kk = 0; kk < 2; ++kk) {
            bf16x8 a[4], b[4];
            const int kbase = kk * 32 + (lane >> 4) * 8;
#pragma unroll
            for (int m = 0; m < 4; ++m)
                a[m] = *reinterpret_cast<const bf16x8*>((char*)As + tile_byte(wr + m * 16 + (lane & 15), kbase));
#pragma unroll
            for (int n = 0; n < 4; ++n) {
                int col = wc + n * 16 + (lane & 15);
                union { unsigned short u[8]; bf16x8 v; } t;
#pragma unroll
                for (int j = 0; j < 8; ++j) t.u[j] = Bs[(kbase + j) * 130 + col];
                b[n] = t.v;
            }
#pragma unroll
            for (int m = 0; m < 4; ++m)
#pragma unroll
                for (int n = 0; n < 4; ++n)
                    acc[m][n] = __builtin_amdgcn_mfma_f32_16x16x32_bf16(a[m], b[n], acc[m][n], 0, 0, 0);
        }
        __syncthreads();
    }
#pragma unroll
    for (int m = 0; m < 4; ++m)
#pragma unroll
        for (int j = 0; j < 4; ++j) {
            int grow = bm + wr + m * 16 + (lane >> 4) * 4 + j;
            float* cr = C + (size_t)grow * N + bn + wc + (lane & 15);
#pragma unroll
            for (int n = 0; n < 4; ++n) cr[n * 16] = acc[m][n][j];
        }
}

// ============================================================================
extern "C" void kernel_launch(void* const* d_in, const int* in_sizes, int n_in,
                              void* d_out, int out_size, void* d_ws, size_t ws_size,
                              hipStream_t stream)
{
    (void)in_sizes; (void)n_in; (void)out_size;
    const float* dec = (const float*)d_in[0];   // [16,512,1024]
    const float* enc = (const float*)d_in[1];   // [16,2048,1024]
    const float* W   = (const float*)d_in[2];   // [1024,1024]

    float* ctx   = (float*)d_out;                            // [16,512,1024]
    float* align = (float*)d_out + (size_t)16 * 512 * 1024;  // [16,512,2048]

    const size_t NEED_FAST = 160ULL * 1048576ULL;  // enc_h + encT + align_h

    if (ws_size >= NEED_FAST) {
        unsigned short* enc_h   = (unsigned short*)d_ws;             // 64 MiB
        unsigned short* encT    = enc_h + 33554432ULL;               // 64 MiB
        unsigned short* align_h = encT + 33554432ULL;                // 32 MiB
        unsigned short* dproj_h = (unsigned short*)d_out;            // ctx region (dead until K4)
        unsigned short* dproj_l = dproj_h + 8388608ULL;
        unsigned short* dec_h   = (unsigned short*)align;            // align region (dead until K2)
        unsigned short* dec_l   = dec_h + 8388608ULL;
        unsigned short* W_h     = dec_l + 8388608ULL;

        // P0: enc -> enc_h + encT (fused transpose); dec h/l; W h only
        split_enc_T<<<dim3(32, 16, 16), 256, 0, stream>>>(enc, enc_h, encT);
        splitf16<<<4096, 256, 0, stream>>>(dec, dec_h, dec_l, 1048576);
        splitf16<<<512, 256, 0, stream>>>(W, W_h, nullptr, 131072);

        // K1: dproj = dec @ W_h^T  (M=8192, N=1024, K=1024) -> fp16 h/l planes
        gemm_wide<2, 1, 4><<<256, 512, 0, stream>>>(
            dec_h, dec_l, 0, W_h, 0,
            nullptr, dproj_h, dproj_l, 0, 8192, 1024, 1024);

        // K2: score = dproj @ enc_h^T per batch (M=512, N=2048, K=1024) -> align
        // 3-buffer counted-vmcnt (T4) at the proven BM=256 geometry
        gemm_k2_3buf<<<256, 512, 0, stream>>>(
            dproj_h, dproj_l, 512LL * 1024, enc_h, 2048LL * 1024,
            align, 512LL * 2048, 512, 2048, 1024);

        // K3: softmax + fp16 copy
        softmax_rows<<<8192, 256, 0, stream>>>(align, align_h);

        // K4: ctx = align_h @ encT^T per batch (M=512, N=1024, K=2048)
        gemm_wide<1, 0, 4><<<256, 512, 0, stream>>>(
            align_h, nullptr, 512LL * 2048, encT, 1024LL * 2048,
            ctx, nullptr, nullptr, 512LL * 1024, 512, 1024, 2048);
    } else {
        // round-1 fallback (needs 32 MiB ws)
        float* dproj = (float*)d_ws;
        gemm_bt_x3<<<dim3(8, 64, 1), 256, 0, stream>>>(
            dec, 0, W, 0, dproj, 0, 8192, 1024, 1024);
        gemm_bt_x3<<<dim3(16, 4, 16), 256, 0, stream>>>(
            dproj, 512LL * 1024, enc, 2048LL * 1024, align, 512LL * 2048, 512, 2048, 1024);
        softmax_rows<<<8192, 256, 0, stream>>>(align, nullptr);
        gemm_nn_bf16<<<dim3(8, 4, 16), 256, 0, stream>>>(
            align, 512LL * 2048, enc, 2048LL * 1024, ctx, 512LL * 1024, 512, 1024, 2048);
    }
}